// Round 3
// baseline (936.017 us; speedup 1.0000x reference)
//
#include <hip/hip_runtime.h>
#include <stdint.h>

typedef unsigned int u32;
typedef unsigned long long u64;
typedef _Float16 f16;
typedef __attribute__((ext_vector_type(8))) _Float16 f16x8;
typedef __attribute__((ext_vector_type(4))) _Float16 f16x4;
typedef __attribute__((ext_vector_type(2))) _Float16 f16x2;
typedef __attribute__((ext_vector_type(4))) float f32x4;

#define MFMA16(a, b, c) __builtin_amdgcn_mfma_f32_16x16x32_f16((a), (b), (c), 0, 0, 0)
#define MARGIN 2.0f

__device__ __forceinline__ u32 ford(float x) { u32 u = __float_as_uint(x); return (u & 0x80000000u) ? ~u : (u | 0x80000000u); }
__device__ __forceinline__ float iford(u32 v) { u32 u = (v & 0x80000000u) ? (v & 0x7FFFFFFFu) : ~v; return __uint_as_float(u); }
__device__ __forceinline__ int xswz(int i, int n) { return (i & 7) * (n >> 3) + (i >> 3); }  // n%8==0

// tiled-swizzled element offset: operand [rows][K], chunks of 128x64 f16 (16KB),
// within-chunk element = row*64 + (col ^ ((row&7)<<3))  (== byte ^ ((row&7)<<4))
__device__ __forceinline__ size_t tswz(int r, int k, int KT) {
  return ((size_t)((r >> 7) * KT + (k >> 6)) << 13) + (size_t)((r & 127) << 6) +
         (size_t)((k & 63) ^ ((r & 7) << 3));
}

typedef __attribute__((address_space(1))) const unsigned char ga_t;
typedef __attribute__((address_space(3))) unsigned char la_t;
__device__ __forceinline__ void gl16(const void* g, void* l) {
  __builtin_amdgcn_global_load_lds((ga_t*)g, (la_t*)l, 16, 0, 0);
}

template <int NT>
__device__ __forceinline__ void stg_tile(const f16* g, char* s, int wid, int lane) {
#pragma unroll
  for (int it = 0; it < 16384 / (NT * 16); ++it) {
    const int u = it * (NT * 16) + wid * 1024;
    gl16((const char*)g + u + lane * 16, s + u);
  }
}

// ---------------------------------------------------------------------------
// NT-GEMM on pre-tiled pre-swizzled f16 operands, BM=BN=128, BK=64,
// global_load_lds staging, double-buffered LDS, one vmcnt(0)+barrier per K-tile.
// MODE 0 (K1, 512 thr): 3-pass split (A=x0 hi/lo, B=w_in hi/lo); out f16 hi/lo tiled.
// MODE 1 (Ep): out f16 linear.   MODE 2 (gram): sum(C^2) -> fixed-point atomic.
// MODE 3 (screen): score=esq-2S, per-row margin candidates.
// MODE 4 (y): out fp32 + b_lin[m] + seq_last[n].
// ---------------------------------------------------------------------------
template <int MODE>
__global__ __launch_bounds__((MODE == 0 ? 512 : 256), (MODE == 0 ? 1 : 2)) void gemm_g(
    const f16* __restrict__ At, const f16* __restrict__ Alt,
    const f16* __restrict__ Bt, const f16* __restrict__ Blt,
    int ktiles, long long sAz, long long sBz,
    void* __restrict__ out0, void* __restrict__ out1,
    const float* __restrict__ bias, const float* __restrict__ aux,
    u64* __restrict__ slots) {
  constexpr bool K1 = (MODE == 0);
  constexpr int NT = K1 ? 512 : 256;
  constexpr int MT = K1 ? 2 : 4;
  constexpr int LDS_SZ = K1 ? 131072 : (MODE == 3 ? 74240 : 65536);
  __shared__ char lds[LDS_SZ];

  const int tid = threadIdx.x;
  const int lane = tid & 63, wid = tid >> 6;
  const int wm = wid >> 1, wn = wid & 1;

  int blkm, blkn, z = 0;
  if constexpr (MODE == 0) { int s = xswz(blockIdx.x, 256); blkn = s & 3; blkm = s >> 2; }
  else if constexpr (MODE == 1) { int s = xswz(blockIdx.x, 128); blkn = s & 3; blkm = (s >> 2) & 7; z = s >> 5; }
  else if constexpr (MODE == 2) { int s = xswz(blockIdx.x, 64); blkn = s & 3; blkm = (s >> 2) & 3; z = s >> 4; }
  else if constexpr (MODE == 3) { int s = xswz(blockIdx.x, 512); blkn = s & 7; blkm = s >> 3; }
  else { int s = xswz(blockIdx.x, 768); int r2 = s % 24; blkm = r2 % 6; blkn = r2 / 6; z = s / 24; }

  if constexpr (MODE == 3) {
    u64* candL = (u64*)(lds + 65536);
    int* cntL = (int*)(lds + 73728);
    for (int i = tid; i < 1024; i += 256) candL[i] = ~0ull;
    if (tid < 128) cntL[tid] = 0;
  }

  const long long cstride = (long long)ktiles << 13;  // chunk elems per 128-row band
  const f16* Ab = At + (size_t)z * sAz + (size_t)blkm * cstride;
  const f16* Bb = Bt + (size_t)z * sBz + (size_t)blkn * cstride;
  const f16* Alb = K1 ? Alt + (size_t)blkm * cstride : nullptr;
  const f16* Blb = K1 ? Blt + (size_t)blkn * cstride : nullptr;

  f32x4 acc[MT][4];
#pragma unroll
  for (int i = 0; i < MT; ++i)
#pragma unroll
    for (int j = 0; j < 4; ++j) acc[i][j] = f32x4{0.f, 0.f, 0.f, 0.f};

  // LDS regions: Ah | (Al) | Bh | (Bl), each 2x16KB double-buffered
  char* sAh = lds;
  char* sAl = K1 ? lds + 32768 : nullptr;
  char* sBh = K1 ? lds + 65536 : lds + 32768;
  char* sBl = K1 ? lds + 98304 : nullptr;

  // prologue: stage k-tile 0 into buf 0
  stg_tile<NT>(Ab, sAh, wid, lane);
  stg_tile<NT>(Bb, sBh, wid, lane);
  if constexpr (K1) {
    stg_tile<NT>(Alb, sAl, wid, lane);
    stg_tile<NT>(Blb, sBl, wid, lane);
  }
  asm volatile("s_waitcnt vmcnt(0)" ::: "memory");
  __syncthreads();

  int cur = 0;
  for (int kc = 0; kc < ktiles; ++kc) {
    if (kc + 1 < ktiles) {  // prefetch next k-tile into other buffer
      const size_t co = (size_t)(kc + 1) << 13;
      const int nb = (cur ^ 1) << 14;
      stg_tile<NT>(Ab + co, sAh + nb, wid, lane);
      stg_tile<NT>(Bb + co, sBh + nb, wid, lane);
      if constexpr (K1) {
        stg_tile<NT>(Alb + co, sAl + nb, wid, lane);
        stg_tile<NT>(Blb + co, sBl + nb, wid, lane);
      }
    }
    const int cb = cur << 14;
#pragma unroll
    for (int ks = 0; ks < 2; ++ks) {
      const int kb = (ks << 6) + ((lane >> 4) << 4);
      f16x8 ah[MT], al[MT];
#pragma unroll
      for (int mt = 0; mt < MT; ++mt) {
        const int rr = wm * (MT * 16) + mt * 16 + (lane & 15);
        const int o = cb + rr * 128 + (kb ^ ((rr & 7) << 4));
        ah[mt] = *(const f16x8*)(sAh + o);
        if constexpr (K1) al[mt] = *(const f16x8*)(sAl + o);
      }
#pragma unroll
      for (int nt = 0; nt < 4; ++nt) {
        const int rn = wn * 64 + nt * 16 + (lane & 15);
        const int o = cb + rn * 128 + (kb ^ ((rn & 7) << 4));
        f16x8 bh = *(const f16x8*)(sBh + o);
        f16x8 bl;
        if constexpr (K1) bl = *(const f16x8*)(sBl + o);
#pragma unroll
        for (int mt = 0; mt < MT; ++mt) {
          if constexpr (K1) {
            acc[mt][nt] = MFMA16(al[mt], bh, acc[mt][nt]);
            acc[mt][nt] = MFMA16(ah[mt], bl, acc[mt][nt]);
          }
          acc[mt][nt] = MFMA16(ah[mt], bh, acc[mt][nt]);
        }
      }
    }
    asm volatile("s_waitcnt vmcnt(0)" ::: "memory");
    __syncthreads();
    cur ^= 1;
  }

  // ---- epilogues ---- C/D: col = lane&15, row = (lane>>4)*4 + reg
  if constexpr (MODE == 0) {
    f16* fht = (f16*)out0;
    f16* flt = (f16*)out1;
#pragma unroll
    for (int nt = 0; nt < 4; ++nt) {
      const int gc = blkn * 128 + wn * 64 + nt * 16 + (lane & 15);
      const float bv = bias[gc];
#pragma unroll
      for (int mt = 0; mt < MT; ++mt)
#pragma unroll
        for (int r = 0; r < 4; ++r) {
          const int grow = blkm * 128 + wm * 32 + mt * 16 + ((lane >> 4) << 2) + r;
          const float v = acc[mt][nt][r] * 6.103515625e-05f + bv;  // /16384 exact
          const f16 hv = (f16)v;
          const size_t off = tswz(grow, gc, 8);
          fht[off] = hv;
          flt[off] = (f16)(v - (float)hv);
        }
    }
  } else if constexpr (MODE == 1) {
    f16* o = (f16*)out0 + (size_t)z * 524288;
#pragma unroll
    for (int nt = 0; nt < 4; ++nt) {
      const int gc = blkn * 128 + wn * 64 + nt * 16 + (lane & 15);
#pragma unroll
      for (int mt = 0; mt < 4; ++mt)
#pragma unroll
        for (int r = 0; r < 4; ++r) {
          const size_t grow = (size_t)blkm * 128 + wm * 64 + mt * 16 + ((lane >> 4) << 2) + r;
          o[grow * 512 + gc] = (f16)acc[mt][nt][r];
        }
    }
  } else if constexpr (MODE == 2) {
    float ssum = 0.f;
#pragma unroll
    for (int mt = 0; mt < 4; ++mt)
#pragma unroll
      for (int nt = 0; nt < 4; ++nt)
#pragma unroll
        for (int r = 0; r < 4; ++r) ssum += acc[mt][nt][r] * acc[mt][nt][r];
#pragma unroll
    for (int o = 1; o < 64; o <<= 1) ssum += __shfl_xor(ssum, o);
    float* wp = (float*)lds;
    if (lane == 0) wp[wid] = ssum;
    __syncthreads();
    if (tid == 0) {
      float p = wp[0] + wp[1] + wp[2] + wp[3];
      atomicAdd(slots + (blockIdx.x & 63), (u64)llrintf(p * 16777216.f));
    }
  } else if constexpr (MODE == 3) {
    u64* candL = (u64*)(lds + 65536);
    int* cntL = (int*)(lds + 73728);
    u64* candG = (u64*)out0;
    float escol[4];
    int cg[4];
#pragma unroll
    for (int nt = 0; nt < 4; ++nt) {
      cg[nt] = blkn * 128 + wn * 64 + nt * 16 + (lane & 15);
      escol[nt] = aux[cg[nt]];
    }
#pragma unroll
    for (int mt = 0; mt < 4; ++mt)
#pragma unroll
      for (int r = 0; r < 4; ++r) {
        const int row_l = wm * 64 + mt * 16 + ((lane >> 4) << 2) + r;
        float vals[4];
        u64 pk[4];
        u64 mn = ~0ull;
#pragma unroll
        for (int nt = 0; nt < 4; ++nt) {
          const float v = escol[nt] - 2.0f * acc[mt][nt][r];
          vals[nt] = v;
          const u64 p = ((u64)ford(v) << 32) | (u32)cg[nt];
          pk[nt] = p;
          if (p < mn) mn = p;
        }
#pragma unroll
        for (int o = 1; o < 16; o <<= 1) {
          const u64 t = __shfl_xor(mn, o);
          if (t < mn) mn = t;
        }
        const float lim = iford((u32)(mn >> 32)) + MARGIN;
#pragma unroll
        for (int nt = 0; nt < 4; ++nt)
          if (vals[nt] <= lim) {
            const int p = atomicAdd(&cntL[row_l], 1);
            if (p < 8) candL[(row_l << 3) + p] = pk[nt];
          }
      }
    __syncthreads();
#pragma unroll
    for (int j = 0; j < 4; ++j) {
      const int idx = tid * 4 + j;
      const int row_l = idx >> 3, slot = idx & 7;
      candG[(((size_t)blkm * 128 + row_l) * 8 + blkn) * 8 + slot] = candL[idx];
    }
  } else {  // MODE 4
    float* oy = (float*)out0 + (size_t)z * 368640;
    const float* xseq = aux + (size_t)z * 524288 + 523776;
    float sl[4];
    int gd[4];
#pragma unroll
    for (int nt = 0; nt < 4; ++nt) {
      gd[nt] = blkn * 128 + wn * 64 + nt * 16 + (lane & 15);
      sl[nt] = xseq[gd[nt]];
    }
#pragma unroll
    for (int mt = 0; mt < 4; ++mt)
#pragma unroll
      for (int r = 0; r < 4; ++r) {
        const int p = blkm * 128 + wm * 64 + mt * 16 + ((lane >> 4) << 2) + r;
        if (p < 720) {
          const float bp = bias[p];
#pragma unroll
          for (int nt = 0; nt < 4; ++nt) oy[(size_t)p * 512 + gd[nt]] = acc[mt][nt][r] + bp + sl[nt];
        }
      }
  }
}

// ---------------------------------------------------------------------------
// Rescore: exact fp64 distances (f = fhi+flo fp32 vs fp32 embed) over margin set.
// ---------------------------------------------------------------------------
__global__ __launch_bounds__(256, 4) void rescore_k(
    const u64* __restrict__ candG, const f16* __restrict__ fht,
    const f16* __restrict__ flt, const float* __restrict__ embedH, int n0, int h,
    int* __restrict__ indw, float* __restrict__ indout, u64* __restrict__ cslots) {
  const int tid = threadIdx.x, lane = tid & 63, wid = tid >> 6;
  const int r = blockIdx.x * 4 + wid;  // [0,8192)
  u64 cu = candG[(size_t)r * 64 + lane];
  u64 mn = cu;
#pragma unroll
  for (int o = 1; o < 64; o <<= 1) { const u64 t = __shfl_xor(mn, o); if (t < mn) mn = t; }
  const float lim = iford((u32)(mn >> 32)) + MARGIN;
  const bool pass = iford((u32)(cu >> 32)) <= lim;  // empty slots -> NaN -> false
  u64 mask = __ballot(pass);
  const int row = r & 127, rt = r >> 7;
  const int kt = lane >> 3, grp = lane & 7;
  // read position grp in the swizzled chunk; its logical d-group is grp^(row&7)
  const size_t fo = ((size_t)(rt * 8 + kt) << 13) + (size_t)(row << 6) + (size_t)(grp << 3);
  const int dbase = kt * 64 + ((grp ^ (row & 7)) << 3);
  float fv[8];
  {
    const f16x8 hv = *(const f16x8*)(fht + fo);
    const f16x8 lv = *(const f16x8*)(flt + fo);
#pragma unroll
    for (int j = 0; j < 8; ++j) fv[j] = (float)hv[j] + (float)lv[j];
  }
  double bestd = 1e300;
  int bestc = 0x7FFFFFFF;
  while (mask) {
    const int src = __ffsll((unsigned long long)mask) - 1;
    mask &= mask - 1;
    const int c = (int)(u32)__shfl(cu, src);
    const float* e = embedH + (size_t)c * 512 + dbase;
    const float4 e0 = *(const float4*)e, e1 = *(const float4*)(e + 4);
    const float ev[8] = {e0.x, e0.y, e0.z, e0.w, e1.x, e1.y, e1.z, e1.w};
    double sd = 0.0;
#pragma unroll
    for (int j = 0; j < 8; ++j) { const double d = (double)fv[j] - (double)ev[j]; sd += d * d; }
#pragma unroll
    for (int o = 1; o < 64; o <<= 1) sd += __shfl_xor(sd, o);
    if (sd < bestd || (sd == bestd && c < bestc)) { bestd = sd; bestc = c; }
  }
  if (lane == 0) {
    const int n = n0 + r;
    indw[(size_t)n * 4 + h] = bestc;
    indout[(size_t)n * 4 + h] = (float)bestc;
    atomicAdd(cslots + (blockIdx.x & 255), (u64)llrint(bestd * 65536.0));
  }
}

// quantized^T gather -> tiled-swizzled qTt[b]: rows=d (512), k=s (1024), KT=16
__global__ __launch_bounds__(256) void quantize_qT(
    const int* __restrict__ indw, const f16* __restrict__ Ep,
    const float* __restrict__ b_out, f16* __restrict__ qTt) {
  const int tid = threadIdx.x;
  const int b = blockIdx.x >> 4, s0 = (blockIdx.x & 15) << 6;
  __shared__ int inds[64][4];
  inds[tid >> 2][tid & 3] = indw[(size_t)(b * 1024 + s0 + (tid >> 2)) * 4 + (tid & 3)];
  __syncthreads();
  const int d0 = tid * 2;
  const float ba0 = b_out[d0], ba1 = b_out[d0 + 1];
  u32 r0[32], r1[32];
  f16 t0 = (f16)0.f, t1 = (f16)0.f;
#pragma unroll
  for (int ss = 0; ss < 64; ++ss) {
    float a0 = ba0, a1 = ba1;
#pragma unroll
    for (int h = 0; h < 4; ++h) {
      const int c = inds[ss][h];
      const f16x2 p = *(const f16x2*)(Ep + (((size_t)h * 1024 + c) * 512 + d0));
      a0 += (float)p[0];
      a1 += (float)p[1];
    }
    const f16 q0 = (f16)a0, q1 = (f16)a1;
    if (ss & 1) {
      f16x2 w0; w0[0] = t0; w0[1] = q0; __builtin_memcpy(&r0[ss >> 1], &w0, 4);
      f16x2 w1; w1[0] = t1; w1[1] = q1; __builtin_memcpy(&r1[ss >> 1], &w1, 4);
    } else { t0 = q0; t1 = q1; }
  }
  const size_t cbase = (size_t)b * 524288 + ((size_t)((d0 >> 7) * 16 + (s0 >> 6)) << 13);
  const size_t b0 = cbase + (size_t)((d0 & 127) << 6);
  const size_t b1 = cbase + (size_t)(((d0 + 1) & 127) << 6);
#pragma unroll
  for (int i = 0; i < 8; ++i) {
    uint4 v; v.x = r0[4 * i]; v.y = r0[4 * i + 1]; v.z = r0[4 * i + 2]; v.w = r0[4 * i + 3];
    *(uint4*)(qTt + b0 + ((size_t)(i ^ (d0 & 7)) << 3)) = v;
  }
#pragma unroll
  for (int i = 0; i < 8; ++i) {
    uint4 v; v.x = r1[4 * i]; v.y = r1[4 * i + 1]; v.z = r1[4 * i + 2]; v.w = r1[4 * i + 3];
    *(uint4*)(qTt + b1 + ((size_t)(i ^ ((d0 + 1) & 7)) << 3)) = v;
  }
}

// ---- prep kernels (all emit tiled-swizzled f16) ----
__global__ __launch_bounds__(256) void prep_x0q(const float* __restrict__ x, int n0,
                                                f16* __restrict__ ht, f16* __restrict__ lt) {
  const int id = blockIdx.x * 256 + threadIdx.x;  // 8192*64 groups
  const int k8 = id & 63, r = id >> 6;
  const int n = n0 + r, b = n >> 10;
  const float* ap = x + (size_t)n * 512 + k8 * 8;
  const float* sp = x + (size_t)b * 524288 + 523776 + k8 * 8;
  const float4 a0 = *(const float4*)ap, a1 = *(const float4*)(ap + 4);
  const float4 s0 = *(const float4*)sp, s1 = *(const float4*)(sp + 4);
  const float v[8] = {(a0.x - s0.x) * 16.f, (a0.y - s0.y) * 16.f, (a0.z - s0.z) * 16.f,
                      (a0.w - s0.w) * 16.f, (a1.x - s1.x) * 16.f, (a1.y - s1.y) * 16.f,
                      (a1.z - s1.z) * 16.f, (a1.w - s1.w) * 16.f};
  f16x8 hv, lv;
#pragma unroll
  for (int j = 0; j < 8; ++j) { const f16 h = (f16)v[j]; hv[j] = h; lv[j] = (f16)(v[j] - (float)h); }
  const size_t off = tswz(r, k8 * 8, 8);
  *(f16x8*)(ht + off) = hv;
  *(f16x8*)(lt + off) = lv;
}

__global__ __launch_bounds__(256) void prep_win(const float* __restrict__ src,
                                                f16* __restrict__ ht, f16* __restrict__ lt) {
  const int id = blockIdx.x * 256 + threadIdx.x;  // 2048*64
  const int k8 = id & 63, rg = id >> 6;
  const int h = rg >> 9, i = rg & 511;
  const float* ap = src + (size_t)rg * 512 + k8 * 8;
  const float4 a0 = *(const float4*)ap, a1 = *(const float4*)(ap + 4);
  const float v[8] = {a0.x * 1024.f, a0.y * 1024.f, a0.z * 1024.f, a0.w * 1024.f,
                      a1.x * 1024.f, a1.y * 1024.f, a1.z * 1024.f, a1.w * 1024.f};
  f16x8 hv, lv;
#pragma unroll
  for (int j = 0; j < 8; ++j) { const f16 h2 = (f16)v[j]; hv[j] = h2; lv[j] = (f16)(v[j] - (float)h2); }
  const size_t off = (size_t)h * 262144 + tswz(i, k8 * 8, 8);
  *(f16x8*)(ht + off) = hv;
  *(f16x8*)(lt + off) = lv;
}

__global__ __launch_bounds__(256) void prep_embed_k(const float* __restrict__ em,
                                                    f16* __restrict__ eft,
                                                    float* __restrict__ esq,
                                                    float* __restrict__ invn) {
  const int tid = threadIdx.x, lane = tid & 63, wid = tid >> 6;
  const int row = blockIdx.x * 4 + wid;  // 0..4095 = h*1024+c
  const int h = row >> 10, c = row & 1023;
  const float* er = em + (size_t)row * 512 + lane * 8;
  const float4 a = *(const float4*)er, b = *(const float4*)(er + 4);
  f16x8 v;
  v[0] = (f16)a.x; v[1] = (f16)a.y; v[2] = (f16)a.z; v[3] = (f16)a.w;
  v[4] = (f16)b.x; v[5] = (f16)b.y; v[6] = (f16)b.z; v[7] = (f16)b.w;
  *(f16x8*)(eft + (size_t)h * 524288 + tswz(c, lane * 8, 8)) = v;
  float s = a.x * a.x + a.y * a.y + a.z * a.z + a.w * a.w +
            b.x * b.x + b.y * b.y + b.z * b.z + b.w * b.w;
#pragma unroll
  for (int o = 1; o < 64; o <<= 1) s += __shfl_xor(s, o);
  if (lane == 0) { esq[row] = s; invn[row] = 1.0f / sqrtf(s); }
}

__global__ __launch_bounds__(256) void prep_wout(const float* __restrict__ src,
                                                 f16* __restrict__ dst) {
  const int id = blockIdx.x * 256 + threadIdx.x;  // 2048*64
  const int k8 = id & 63, rg = id >> 6;
  const int d = rg & 511, h = rg >> 9;
  const float* ap = src + (size_t)d * 2048 + h * 512 + k8 * 8;
  const float4 a0 = *(const float4*)ap, a1 = *(const float4*)(ap + 4);
  f16x8 v;
  v[0] = (f16)a0.x; v[1] = (f16)a0.y; v[2] = (f16)a0.z; v[3] = (f16)a0.w;
  v[4] = (f16)a1.x; v[5] = (f16)a1.y; v[6] = (f16)a1.z; v[7] = (f16)a1.w;
  *(f16x8*)(dst + (size_t)h * 262144 + tswz(d, k8 * 8, 8)) = v;
}

__global__ __launch_bounds__(256) void prep_wlin(const float* __restrict__ src,
                                                 f16* __restrict__ dst) {
  const int id = blockIdx.x * 256 + threadIdx.x;  // 768*128
  const int k8 = id & 127, row = id >> 7;
  float4 a0 = {0.f, 0.f, 0.f, 0.f}, a1 = a0;
  if (row < 720) {
    const float* ap = src + (size_t)row * 1024 + k8 * 8;
    a0 = *(const float4*)ap;
    a1 = *(const float4*)(ap + 4);
  }
  f16x8 v;
  v[0] = (f16)a0.x; v[1] = (f16)a0.y; v[2] = (f16)a0.z; v[3] = (f16)a0.w;
  v[4] = (f16)a1.x; v[5] = (f16)a1.y; v[6] = (f16)a1.z; v[7] = (f16)a1.w;
  *(f16x8*)(dst + tswz(row, k8 * 8, 16)) = v;
}

__global__ __launch_bounds__(256) void prep_normT(const float* __restrict__ em,
                                                  const float* __restrict__ invn,
                                                  f16* __restrict__ nTt) {
  __shared__ float t[64 * 65];
  const int tid = threadIdx.x;
  const int bx = blockIdx.x;  // 512
  const int h = bx >> 7, rem = bx & 127, cb = rem >> 3, db = rem & 7;
  const int c0 = cb * 64, d0 = db * 64;
  const int j = tid & 63, i0 = tid >> 6;
#pragma unroll
  for (int p = 0; p < 16; ++p) {
    const int i = p * 4 + i0;
    t[i * 65 + j] = em[(size_t)h * 524288 + (size_t)(c0 + i) * 512 + d0 + j] * invn[h * 1024 + c0 + i];
  }
  __syncthreads();
#pragma unroll
  for (int p = 0; p < 16; ++p) {
    const int i = p * 4 + i0;
    nTt[(size_t)h * 524288 + tswz(d0 + i, c0 + j, 16)] = (f16)t[j * 65 + i];
  }
}

__global__ void finalize_k(const u64* __restrict__ cs, const u64* __restrict__ gs,
                           float* __restrict__ out) {
  const int lane = threadIdx.x;  // 64
  u64 c = cs[lane] + cs[lane + 64] + cs[lane + 128] + cs[lane + 192];
  u64 g = gs[lane];
#pragma unroll
  for (int o = 1; o < 64; o <<= 1) {
    c += __shfl_xor(c, o);
    g += __shfl_xor(g, o);
  }
  if (lane == 0) {
    const double commit = (double)c / 65536.0 / 67108864.0;
    const double ortho = (double)g / 16777216.0 / 4194304.0 - (1.0 / 1024.0);
    out[11927552] = (float)(commit + 0.8 * ortho);
  }
}

__global__ void ws_fail_k(float* out) {
  if (threadIdx.x == 0) out[11927552] = -777777.0f;  // sentinel: ws too small
}

// ---------------------------------------------------------------------------
extern "C" void kernel_launch(void* const* d_in, const int* in_sizes, int n_in,
                              void* d_out, int out_size, void* d_ws, size_t ws_size,
                              hipStream_t stream) {
  (void)in_sizes; (void)n_in; (void)out_size;
  const float* x = (const float*)d_in[0];
  const float* w_in = (const float*)d_in[1];
  const float* b_in = (const float*)d_in[2];
  const float* embed = (const float*)d_in[3];
  const float* w_out = (const float*)d_in[4];
  const float* b_out = (const float*)d_in[5];
  const float* w_lin = (const float*)d_in[6];
  const float* b_lin = (const float*)d_in[7];
  float* out = (float*)d_out;
  char* ws = (char*)d_ws;

  constexpr size_t OFF_X0H = 0;          // 8MB (per quarter), later aliased by qTt
  constexpr size_t OFF_X0L = 8388608;    // 8MB
  constexpr size_t OFF_FH = 16777216;    // 8MB
  constexpr size_t OFF_FL = 25165824;    // 8MB
  constexpr size_t OFF_CAND = 33554432;  // 4MB (aliases nTt)
  constexpr size_t OFF_WINH = 37748736;  // 2MB
  constexpr size_t OFF_WINL = 39845888;  // 2MB
  constexpr size_t OFF_EFT = 41943040;   // 4MB
  constexpr size_t OFF_WOUT = 46137344;  // 2MB
  constexpr size_t OFF_EP = 48234496;    // 4MB
  constexpr size_t OFF_WLIN = 52428800;  // 1.5MB
  constexpr size_t OFF_ESQ = 54001664;   // 16KB
  constexpr size_t OFF_INVN = 54018048;  // 16KB
  constexpr size_t OFF_INDW = 54034432;  // 512KB
  constexpr size_t OFF_CSL = 54558720;   // 2KB
  constexpr size_t OFF_GSL = 54560768;   // 512B
  constexpr size_t REQUIRED = 54561280;  // ~52MB

  if (ws_size < REQUIRED) {
    ws_fail_k<<<1, 64, 0, stream>>>(out);
    return;
  }

  f16* x0ht = (f16*)(ws + OFF_X0H);
  f16* x0lt = (f16*)(ws + OFF_X0L);
  f16* fht = (f16*)(ws + OFF_FH);
  f16* flt = (f16*)(ws + OFF_FL);
  u64* cand = (u64*)(ws + OFF_CAND);
  f16* nTt = (f16*)(ws + OFF_CAND);  // alias: nTt dead before cand first written
  f16* winhi = (f16*)(ws + OFF_WINH);
  f16* winlo = (f16*)(ws + OFF_WINL);
  f16* eft = (f16*)(ws + OFF_EFT);
  f16* woutt = (f16*)(ws + OFF_WOUT);
  f16* Ep = (f16*)(ws + OFF_EP);
  f16* wlint = (f16*)(ws + OFF_WLIN);
  float* esq = (float*)(ws + OFF_ESQ);
  float* invn = (float*)(ws + OFF_INVN);
  int* indw = (int*)(ws + OFF_INDW);
  u64* cslots = (u64*)(ws + OFF_CSL);
  u64* gslots = (u64*)(ws + OFF_GSL);
  f16* qTt = (f16*)(ws + OFF_X0H);  // alias: x0/f dead after last rescore

  hipMemsetAsync(ws + OFF_CSL, 0, 2560, stream);

  prep_win<<<512, 256, 0, stream>>>(w_in, winhi, winlo);
  prep_embed_k<<<1024, 256, 0, stream>>>(embed, eft, esq, invn);
  prep_normT<<<512, 256, 0, stream>>>(embed, invn, nTt);
  prep_wout<<<512, 256, 0, stream>>>(w_out, woutt);
  prep_wlin<<<384, 256, 0, stream>>>(w_lin, wlint);

  // Ep[h] = embed_h @ w_out_h^T  (f16 linear out)
  gemm_g<1><<<128, 256, 0, stream>>>(eft, nullptr, woutt, nullptr, 8, 524288LL, 262144LL,
                                     Ep, nullptr, nullptr, nullptr, nullptr);
  // ortho: ||N_h^T N_h||_F^2
  gemm_g<2><<<64, 256, 0, stream>>>(nTt, nullptr, nTt, nullptr, 16, 524288LL, 524288LL,
                                    nullptr, nullptr, nullptr, nullptr, gslots);

  for (int q = 0; q < 4; ++q) {
    const int n0 = q * 8192;
    prep_x0q<<<2048, 256, 0, stream>>>(x, n0, x0ht, x0lt);
    for (int h = 0; h < 4; ++h) {
      // f = ((x - seq_last)@w_in_h^T + b_in_h), split-f16 3-pass -> f16 hi/lo tiled
      gemm_g<0><<<256, 512, 0, stream>>>(x0ht, x0lt, winhi + (size_t)h * 262144,
                                         winlo + (size_t)h * 262144, 8, 0LL, 0LL,
                                         fht, flt, b_in + h * 512, nullptr, nullptr);
      // screen scores + margin candidates
      gemm_g<3><<<512, 256, 0, stream>>>(fht, nullptr, eft + (size_t)h * 524288, nullptr,
                                         8, 0LL, 0LL, cand, nullptr, nullptr,
                                         esq + h * 1024, nullptr);
      // exact rescore -> indices + commit d^2
      rescore_k<<<2048, 256, 0, stream>>>(cand, fht, flt, embed + (size_t)h * 524288,
                                          n0, h, indw, out + 11796480, cslots);
    }
  }

  quantize_qT<<<512, 256, 0, stream>>>(indw, Ep, b_out, qTt);
  // y = w_lin @ quantized + b_lin + seq_last
  gemm_g<4><<<768, 256, 0, stream>>>(wlint, nullptr, qTt, nullptr, 16, 0LL, 524288LL,
                                     out, nullptr, b_lin, x, nullptr);
  finalize_k<<<1, 64, 0, stream>>>(cslots, gslots, out);
}

// Round 4
// 751.823 us; speedup vs baseline: 1.2450x; 1.2450x over previous
//
#include <hip/hip_runtime.h>
#include <stdint.h>

typedef unsigned int u32;
typedef unsigned long long u64;
typedef _Float16 f16;
typedef __attribute__((ext_vector_type(8))) _Float16 f16x8;
typedef __attribute__((ext_vector_type(4))) _Float16 f16x4;
typedef __attribute__((ext_vector_type(2))) _Float16 f16x2;
typedef __attribute__((ext_vector_type(4))) float f32x4;

#define MFMA16(a, b, c) __builtin_amdgcn_mfma_f32_16x16x32_f16((a), (b), (c), 0, 0, 0)
#define MARGIN 2.0f

__device__ __forceinline__ u32 ford(float x) { u32 u = __float_as_uint(x); return (u & 0x80000000u) ? ~u : (u | 0x80000000u); }
__device__ __forceinline__ float iford(u32 v) { u32 u = (v & 0x80000000u) ? (v & 0x7FFFFFFFu) : ~v; return __uint_as_float(u); }
__device__ __forceinline__ int xswz(int i, int n) { return (i & 7) * (n >> 3) + (i >> 3); }  // n%8==0

typedef __attribute__((address_space(1))) const unsigned char ga_t;
typedef __attribute__((address_space(3))) unsigned char la_t;
__device__ __forceinline__ void gl16(const void* g, void* l) {
  __builtin_amdgcn_global_load_lds((ga_t*)g, (la_t*)l, 16, 0, 0);
}

// Stage one 128-row x 32-col f16 k-tile (8KB) from plain row-major global into
// linear LDS, applying the inverse bank swizzle on the SOURCE address.
// LDS (r, s16B) holds global 16B-slot s ^ ((r>>1)&3). 2 gl16 per thread.
template <int LDK>
__device__ __forceinline__ void stg8k(const f16* gRowBase, int ktile, char* sdst, int tid) {
#pragma unroll
  for (int it = 0; it < 2; ++it) {
    const int u = (tid + (it << 8)) << 4;  // LDS byte offset in [0, 8192)
    const int r = u >> 6, s = (u >> 4) & 3;
    const char* src = (const char*)gRowBase + (size_t)r * (LDK * 2) + ((size_t)ktile << 6) +
                      (size_t)((s ^ ((r >> 1) & 3)) << 4);
    gl16(src, sdst + u);
  }
}

// ---------------------------------------------------------------------------
// NT-GEMM, plain row-major f16 operands, BM=BN=128, BK=32, 256 thr (4 waves,
// each 64x64 quadrant), global_load_lds + source-side swizzle, LDS dbuf,
// one vmcnt(0)+barrier per k-tile.
// MODE 0 (K1): 3-pass split (A=x0 hi/lo, B=w_in hi/lo all heads); f16 hi/lo out.
// MODE 1 (Ep): out f16 plain.  MODE 2 (gram): sum(C^2) -> fixed-point atomic.
// MODE 3 (screen): score=esq-2S, per-row margin candidates, all heads.
// MODE 4 (y): out fp32 + b_lin[m] + seq_last[n].
// ---------------------------------------------------------------------------
template <int MODE>
__global__ __launch_bounds__(256, (MODE == 0) ? 2 : 3) void gemm2(
    const f16* __restrict__ Ah, const f16* __restrict__ Al,
    const f16* __restrict__ Bh, const f16* __restrict__ Bl,
    int chrows, int ktiles,
    void* __restrict__ out0, void* __restrict__ out1,
    const float* __restrict__ bias, const float* __restrict__ aux,
    u64* __restrict__ slots) {
  constexpr bool K1 = (MODE == 0);
  constexpr int LDK = (MODE == 2 || MODE == 4) ? 1024 : 512;
  constexpr int OPS = K1 ? 4 : 2;
  constexpr int LDS_SZ = (MODE == 3) ? 41472 : (OPS * 16384);
  __shared__ char lds[LDS_SZ];

  const int tid = threadIdx.x;
  const int lane = tid & 63, wid = tid >> 6;
  const int wm = wid >> 1, wn = wid & 1;

  int blkm, blkn, z = 0;
  {
    const int s = xswz(blockIdx.x, gridDim.x);
    if constexpr (MODE == 0) { blkn = s & 15; blkm = s >> 4; }
    else if constexpr (MODE == 1) { blkn = s & 3; blkm = s >> 2; z = blkm >> 3; }
    else if constexpr (MODE == 2) { blkn = s & 3; blkm = (s >> 2) & 3; z = s >> 4; }
    else if constexpr (MODE == 3) { blkn = s & 31; blkm = s >> 5; }
    else { const int r2 = s % 24; blkm = r2 % 6; blkn = r2 / 6; z = s / 24; }
  }

  if constexpr (MODE == 3) {
    u64* candL = (u64*)(lds + 32768);
    int* cntL = (int*)(lds + 40960);
    for (int i = tid; i < 1024; i += 256) candL[i] = ~0ull;
    if (tid < 128) cntL[tid] = 0;
  }

  // operand base pointers (128-row bands)
  const f16 *Ab, *Bb, *Alb = nullptr, *Blb = nullptr;
  if constexpr (MODE == 0) {
    Ab = Ah + (size_t)blkm * 65536;            // x0h [chrows][512]
    Alb = Al + (size_t)blkm * 65536;
    Bb = Bh + (size_t)blkn * 65536;            // winh [2048][512]
    Blb = Bl + (size_t)blkn * 65536;
  } else if constexpr (MODE == 1) {
    Ab = Ah + (size_t)blkm * 65536;            // eft [4096][512]
    Bb = Bh + (size_t)z * 262144 + (size_t)blkn * 65536;  // wout [4][512][512]
  } else if constexpr (MODE == 2) {
    Ab = Ah + (size_t)z * 524288 + (size_t)blkm * 131072;  // nT [4][512][1024]
    Bb = Bh + (size_t)z * 524288 + (size_t)blkn * 131072;
  } else if constexpr (MODE == 3) {
    const int h = blkn >> 3;
    Ab = Ah + ((size_t)h * chrows + (size_t)blkm * 128) * 512;  // fh [4][chrows][512]
    Bb = Bh + (size_t)h * 524288 + (size_t)(blkn & 7) * 65536;  // eft head
  } else {
    Ab = Ah + (size_t)blkm * 131072;           // wlin [768][1024]
    Bb = Bh + (size_t)z * 524288 + (size_t)blkn * 131072;  // qT [32][512][1024]
  }

  f32x4 acc[4][4];
#pragma unroll
  for (int i = 0; i < 4; ++i)
#pragma unroll
    for (int j = 0; j < 4; ++j) acc[i][j] = f32x4{0.f, 0.f, 0.f, 0.f};

  // LDS: [dbuf 2][OPS][8192]; op order: Ah, (Al), Bh, (Bl)
  constexpr int BUF = OPS * 8192;

  stg8k<LDK>(Ab, 0, lds, tid);
  if constexpr (K1) stg8k<LDK>(Alb, 0, lds + 8192, tid);
  stg8k<LDK>(Bb, 0, lds + (K1 ? 16384 : 8192), tid);
  if constexpr (K1) stg8k<LDK>(Blb, 0, lds + 24576, tid);
  asm volatile("s_waitcnt vmcnt(0)" ::: "memory");
  __syncthreads();

  int cur = 0;
  for (int kc = 0; kc < ktiles; ++kc) {
    if (kc + 1 < ktiles) {
      char* nb = lds + (cur ^ 1) * BUF;
      stg8k<LDK>(Ab, kc + 1, nb, tid);
      if constexpr (K1) stg8k<LDK>(Alb, kc + 1, nb + 8192, tid);
      stg8k<LDK>(Bb, kc + 1, nb + (K1 ? 16384 : 8192), tid);
      if constexpr (K1) stg8k<LDK>(Blb, kc + 1, nb + 24576, tid);
    }
    const char* cb = lds + cur * BUF;
    const int sA = 0, sAl = 8192, sB = K1 ? 16384 : 8192, sBl = 24576;
    f16x8 ah[4], al[4];
#pragma unroll
    for (int mt = 0; mt < 4; ++mt) {
      const int rr = wm * 64 + mt * 16 + (lane & 15);
      const int o = rr * 64 + (((lane >> 4) ^ ((rr >> 1) & 3)) << 4);
      ah[mt] = *(const f16x8*)(cb + sA + o);
      if constexpr (K1) al[mt] = *(const f16x8*)(cb + sAl + o);
    }
#pragma unroll
    for (int nt = 0; nt < 4; ++nt) {
      const int rn = wn * 64 + nt * 16 + (lane & 15);
      const int o = rn * 64 + (((lane >> 4) ^ ((rn >> 1) & 3)) << 4);
      const f16x8 bh = *(const f16x8*)(cb + sB + o);
      f16x8 bl;
      if constexpr (K1) bl = *(const f16x8*)(cb + sBl + o);
#pragma unroll
      for (int mt = 0; mt < 4; ++mt) {
        if constexpr (K1) {
          acc[mt][nt] = MFMA16(al[mt], bh, acc[mt][nt]);
          acc[mt][nt] = MFMA16(ah[mt], bl, acc[mt][nt]);
        }
        acc[mt][nt] = MFMA16(ah[mt], bh, acc[mt][nt]);
      }
    }
    asm volatile("s_waitcnt vmcnt(0)" ::: "memory");
    __syncthreads();
    cur ^= 1;
  }

  // ---- epilogues ---- C/D: col = lane&15, row = (lane>>4)*4 + reg
  if constexpr (MODE == 0) {
    f16* fh = (f16*)out0;
    f16* fl = (f16*)out1;
#pragma unroll
    for (int nt = 0; nt < 4; ++nt) {
      const int gc = blkn * 128 + wn * 64 + nt * 16 + (lane & 15);
      const float bv = bias[gc];
      const int h = gc >> 9, d = gc & 511;
#pragma unroll
      for (int mt = 0; mt < 4; ++mt)
#pragma unroll
        for (int r = 0; r < 4; ++r) {
          const int grow = blkm * 128 + wm * 64 + mt * 16 + ((lane >> 4) << 2) + r;
          const float v = acc[mt][nt][r] * 6.103515625e-05f + bv;  // /16384 exact
          const f16 hv = (f16)v;
          const size_t off = ((size_t)h * chrows + grow) * 512 + d;
          fh[off] = hv;
          fl[off] = (f16)(v - (float)hv);
        }
    }
  } else if constexpr (MODE == 1) {
    f16* o = (f16*)out0;  // Ep [4096][512]
#pragma unroll
    for (int nt = 0; nt < 4; ++nt) {
      const int gc = blkn * 128 + wn * 64 + nt * 16 + (lane & 15);
#pragma unroll
      for (int mt = 0; mt < 4; ++mt)
#pragma unroll
        for (int r = 0; r < 4; ++r) {
          const size_t grow = (size_t)blkm * 128 + wm * 64 + mt * 16 + ((lane >> 4) << 2) + r;
          o[grow * 512 + gc] = (f16)acc[mt][nt][r];
        }
    }
  } else if constexpr (MODE == 2) {
    float ssum = 0.f;
#pragma unroll
    for (int mt = 0; mt < 4; ++mt)
#pragma unroll
      for (int nt = 0; nt < 4; ++nt)
#pragma unroll
        for (int r = 0; r < 4; ++r) ssum += acc[mt][nt][r] * acc[mt][nt][r];
#pragma unroll
    for (int o = 1; o < 64; o <<= 1) ssum += __shfl_xor(ssum, o);
    float* wp = (float*)lds;
    if (lane == 0) wp[wid] = ssum;
    __syncthreads();
    if (tid == 0) {
      const float p = wp[0] + wp[1] + wp[2] + wp[3];
      atomicAdd(slots + (blockIdx.x & 63), (u64)llrintf(p * 16777216.f));
    }
  } else if constexpr (MODE == 3) {
    u64* candL = (u64*)(lds + 32768);
    int* cntL = (int*)(lds + 40960);
    u64* candG = (u64*)out0;
    const int h = blkn >> 3;
    float escol[4];
    int cc[4];
#pragma unroll
    for (int nt = 0; nt < 4; ++nt) {
      const int gc = blkn * 128 + wn * 64 + nt * 16 + (lane & 15);  // h*1024 + c
      escol[nt] = aux[gc];
      cc[nt] = gc & 1023;
    }
#pragma unroll
    for (int mt = 0; mt < 4; ++mt)
#pragma unroll
      for (int r = 0; r < 4; ++r) {
        const int row_l = wm * 64 + mt * 16 + ((lane >> 4) << 2) + r;
        float vals[4];
        u64 pk[4];
        u64 mn = ~0ull;
#pragma unroll
        for (int nt = 0; nt < 4; ++nt) {
          const float v = escol[nt] - 2.0f * acc[mt][nt][r];
          vals[nt] = v;
          const u64 p = ((u64)ford(v) << 32) | (u32)cc[nt];
          pk[nt] = p;
          if (p < mn) mn = p;
        }
#pragma unroll
        for (int o = 1; o < 16; o <<= 1) {
          const u64 t = __shfl_xor(mn, o);
          if (t < mn) mn = t;
        }
        const float lim = iford((u32)(mn >> 32)) + MARGIN;
#pragma unroll
        for (int nt = 0; nt < 4; ++nt)
          if (vals[nt] <= lim) {
            const int p = atomicAdd(&cntL[row_l], 1);
            if (p < 8) candL[(row_l << 3) + p] = pk[nt];
          }
      }
    __syncthreads();
#pragma unroll
    for (int j = 0; j < 4; ++j) {
      const int idx = tid * 4 + j;
      const int row_l = idx >> 3, slot = idx & 7;
      const size_t grow = (size_t)blkm * 128 + row_l;
      candG[((size_t)h * chrows + grow) * 64 + (size_t)(blkn & 7) * 8 + slot] = candL[idx];
    }
  } else {  // MODE 4
    float* oy = (float*)out0 + (size_t)z * 368640;
    const float* xseq = aux + (size_t)z * 524288 + 523776;
    float sl[4];
    int gd[4];
#pragma unroll
    for (int nt = 0; nt < 4; ++nt) {
      gd[nt] = blkn * 128 + wn * 64 + nt * 16 + (lane & 15);
      sl[nt] = xseq[gd[nt]];
    }
#pragma unroll
    for (int mt = 0; mt < 4; ++mt)
#pragma unroll
      for (int r = 0; r < 4; ++r) {
        const int p = blkm * 128 + wm * 64 + mt * 16 + ((lane >> 4) << 2) + r;
        if (p < 720) {
          const float bp = bias[p];
#pragma unroll
          for (int nt = 0; nt < 4; ++nt) oy[(size_t)p * 512 + gd[nt]] = acc[mt][nt][r] + bp + sl[nt];
        }
      }
  }
}

// ---------------------------------------------------------------------------
// Rescore: exact fp64 distances (f = fh+fl vs fp32 embed) over margin set.
// One wave per (h,row); all 4 heads in one launch.
// ---------------------------------------------------------------------------
__global__ __launch_bounds__(256, 4) void rescore_k(
    const u64* __restrict__ candG, const f16* __restrict__ fh,
    const f16* __restrict__ fl, const float* __restrict__ embed,
    int n0, int shCH,
    int* __restrict__ indw, float* __restrict__ indout, u64* __restrict__ cslots) {
  const int tid = threadIdx.x, lane = tid & 63, wid = tid >> 6;
  const int r = blockIdx.x * 4 + wid;  // [0, 4*CH): r = h*CH + row
  const int h = r >> shCH, row = r & ((1 << shCH) - 1);
  u64 cu = candG[(size_t)r * 64 + lane];
  u64 mn = cu;
#pragma unroll
  for (int o = 1; o < 64; o <<= 1) { const u64 t = __shfl_xor(mn, o); if (t < mn) mn = t; }
  const float lim = iford((u32)(mn >> 32)) + MARGIN;
  const bool pass = iford((u32)(cu >> 32)) <= lim;  // empty slots -> NaN -> false
  u64 mask = __ballot(pass);
  float fv[8];
  {
    const size_t fo = (size_t)r * 512 + lane * 8;
    const f16x8 hv = *(const f16x8*)(fh + fo);
    const f16x8 lv = *(const f16x8*)(fl + fo);
#pragma unroll
    for (int j = 0; j < 8; ++j) fv[j] = (float)hv[j] + (float)lv[j];
  }
  double bestd = 1e300;
  int bestc = 0x7FFFFFFF;
  while (mask) {
    const int src = __ffsll((unsigned long long)mask) - 1;
    mask &= mask - 1;
    const int c = (int)(u32)__shfl(cu, src);
    const float* e = embed + ((size_t)h * 1024 + c) * 512 + lane * 8;
    const float4 e0 = *(const float4*)e, e1 = *(const float4*)(e + 4);
    const float ev[8] = {e0.x, e0.y, e0.z, e0.w, e1.x, e1.y, e1.z, e1.w};
    double sd = 0.0;
#pragma unroll
    for (int j = 0; j < 8; ++j) { const double d = (double)fv[j] - (double)ev[j]; sd += d * d; }
#pragma unroll
    for (int o = 1; o < 64; o <<= 1) sd += __shfl_xor(sd, o);
    if (sd < bestd || (sd == bestd && c < bestc)) { bestd = sd; bestc = c; }
  }
  if (lane == 0) {
    const int n = n0 + row;
    indw[(size_t)n * 4 + h] = bestc;
    indout[(size_t)n * 4 + h] = (float)bestc;
    atomicAdd(cslots + (blockIdx.x & 255), (u64)llrint(bestd * 65536.0));
  }
}

// quantized^T gather: qT[b][d][s] = f16( b_out[d] + sum_h Ep[h*1024+ind][d] )
__global__ __launch_bounds__(256) void quantize_qT(
    const int* __restrict__ indw, const f16* __restrict__ Ep,
    const float* __restrict__ b_out, f16* __restrict__ qT) {
  const int tid = threadIdx.x;
  const int b = blockIdx.x >> 4, s0 = (blockIdx.x & 15) << 6;
  __shared__ int inds[64][4];
  inds[tid >> 2][tid & 3] = indw[(size_t)(b * 1024 + s0 + (tid >> 2)) * 4 + (tid & 3)];
  __syncthreads();
  const int d0 = tid * 2;
  const float ba0 = b_out[d0], ba1 = b_out[d0 + 1];
  u32 r0[32], r1[32];
  f16 t0 = (f16)0.f, t1 = (f16)0.f;
#pragma unroll
  for (int ss = 0; ss < 64; ++ss) {
    float a0 = ba0, a1 = ba1;
#pragma unroll
    for (int h = 0; h < 4; ++h) {
      const int c = inds[ss][h];
      const f16x2 p = *(const f16x2*)(Ep + (((size_t)h * 1024 + c) * 512 + d0));
      a0 += (float)p[0];
      a1 += (float)p[1];
    }
    const f16 q0 = (f16)a0, q1 = (f16)a1;
    if (ss & 1) {
      f16x2 w0; w0[0] = t0; w0[1] = q0; __builtin_memcpy(&r0[ss >> 1], &w0, 4);
      f16x2 w1; w1[0] = t1; w1[1] = q1; __builtin_memcpy(&r1[ss >> 1], &w1, 4);
    } else { t0 = q0; t1 = q1; }
  }
  const size_t o0 = ((size_t)b * 512 + d0) * 1024 + s0;
#pragma unroll
  for (int i = 0; i < 8; ++i) {
    uint4 v; v.x = r0[4 * i]; v.y = r0[4 * i + 1]; v.z = r0[4 * i + 2]; v.w = r0[4 * i + 3];
    *(uint4*)(qT + o0 + (size_t)i * 8) = v;
  }
  const size_t o1 = o0 + 1024;
#pragma unroll
  for (int i = 0; i < 8; ++i) {
    uint4 v; v.x = r1[4 * i]; v.y = r1[4 * i + 1]; v.z = r1[4 * i + 2]; v.w = r1[4 * i + 3];
    *(uint4*)(qT + o1 + (size_t)i * 8) = v;
  }
}

// ---- prep kernels (all plain row-major outputs) ----
__global__ __launch_bounds__(256) void prep_x0(const float* __restrict__ x, int n0,
                                               f16* __restrict__ ht, f16* __restrict__ lt) {
  const int id = blockIdx.x * 256 + threadIdx.x;  // CH*64 groups of 8
  const int k8 = id & 63, r = id >> 6;
  const int n = n0 + r, b = n >> 10;
  const float* ap = x + (size_t)n * 512 + k8 * 8;
  const float* sp = x + (size_t)b * 524288 + 523776 + k8 * 8;
  const float4 a0 = *(const float4*)ap, a1 = *(const float4*)(ap + 4);
  const float4 s0 = *(const float4*)sp, s1 = *(const float4*)(sp + 4);
  const float v[8] = {(a0.x - s0.x) * 16.f, (a0.y - s0.y) * 16.f, (a0.z - s0.z) * 16.f,
                      (a0.w - s0.w) * 16.f, (a1.x - s1.x) * 16.f, (a1.y - s1.y) * 16.f,
                      (a1.z - s1.z) * 16.f, (a1.w - s1.w) * 16.f};
  f16x8 hv, lv;
#pragma unroll
  for (int j = 0; j < 8; ++j) { const f16 h = (f16)v[j]; hv[j] = h; lv[j] = (f16)(v[j] - (float)h); }
  const size_t off = (size_t)r * 512 + k8 * 8;
  *(f16x8*)(ht + off) = hv;
  *(f16x8*)(lt + off) = lv;
}

__global__ __launch_bounds__(256) void prep_win(const float* __restrict__ src,
                                                f16* __restrict__ hi, f16* __restrict__ lo) {
  const size_t e = ((size_t)blockIdx.x * 256 + threadIdx.x) * 4;  // 2048*512 elems
  const float4 v = *(const float4*)(src + e);
  const float w[4] = {v.x * 1024.f, v.y * 1024.f, v.z * 1024.f, v.w * 1024.f};
  f16x4 hv, lv;
#pragma unroll
  for (int j = 0; j < 4; ++j) { const f16 h = (f16)w[j]; hv[j] = h; lv[j] = (f16)(w[j] - (float)h); }
  *(f16x4*)(hi + e) = hv;
  *(f16x4*)(lo + e) = lv;
}

__global__ __launch_bounds__(256) void prep_embed_k(const float* __restrict__ em,
                                                    f16* __restrict__ ef,
                                                    float* __restrict__ esq,
                                                    float* __restrict__ invn) {
  const int tid = threadIdx.x, lane = tid & 63, wid = tid >> 6;
  const int row = blockIdx.x * 4 + wid;  // 0..4095 = h*1024+c
  const float* er = em + (size_t)row * 512 + lane * 8;
  const float4 a = *(const float4*)er, b = *(const float4*)(er + 4);
  f16x8 v;
  v[0] = (f16)a.x; v[1] = (f16)a.y; v[2] = (f16)a.z; v[3] = (f16)a.w;
  v[4] = (f16)b.x; v[5] = (f16)b.y; v[6] = (f16)b.z; v[7] = (f16)b.w;
  *(f16x8*)(ef + (size_t)row * 512 + lane * 8) = v;
  float s = a.x * a.x + a.y * a.y + a.z * a.z + a.w * a.w +
            b.x * b.x + b.y * b.y + b.z * b.z + b.w * b.w;
#pragma unroll
  for (int o = 1; o < 64; o <<= 1) s += __shfl_xor(s, o);
  if (lane == 0) { esq[row] = s; invn[row] = 1.0f / sqrtf(s); }
}

__global__ __launch_bounds__(256) void prep_wout(const float* __restrict__ src,
                                                 f16* __restrict__ dst) {
  const int id = blockIdx.x * 256 + threadIdx.x;  // 2048*64
  const int k8 = id & 63, rg = id >> 6;
  const int d = rg & 511, h = rg >> 9;
  const float* ap = src + (size_t)d * 2048 + h * 512 + k8 * 8;
  const float4 a0 = *(const float4*)ap, a1 = *(const float4*)(ap + 4);
  f16x8 v;
  v[0] = (f16)a0.x; v[1] = (f16)a0.y; v[2] = (f16)a0.z; v[3] = (f16)a0.w;
  v[4] = (f16)a1.x; v[5] = (f16)a1.y; v[6] = (f16)a1.z; v[7] = (f16)a1.w;
  *(f16x8*)(dst + (size_t)h * 262144 + (size_t)d * 512 + k8 * 8) = v;
}

__global__ __launch_bounds__(256) void prep_wlin(const float* __restrict__ src,
                                                 f16* __restrict__ dst) {
  const int id = blockIdx.x * 256 + threadIdx.x;  // 768*128
  const int k8 = id & 127, row = id >> 7;
  float4 a0 = {0.f, 0.f, 0.f, 0.f}, a1 = a0;
  if (row < 720) {
    const float* ap = src + (size_t)row * 1024 + k8 * 8;
    a0 = *(const float4*)ap;
    a1 = *(const float4*)(ap + 4);
  }
  f16x8 v;
  v[0] = (f16)a0.x; v[1] = (f16)a0.y; v[2] = (f16)a0.z; v[3] = (f16)a0.w;
  v[4] = (f16)a1.x; v[5] = (f16)a1.y; v[6] = (f16)a1.z; v[7] = (f16)a1.w;
  *(f16x8*)(dst + (size_t)row * 1024 + k8 * 8) = v;
}

__global__ __launch_bounds__(256) void prep_normT(const float* __restrict__ em,
                                                  const float* __restrict__ invn,
                                                  f16* __restrict__ nT) {
  __shared__ float t[64 * 65];
  const int tid = threadIdx.x;
  const int bx = blockIdx.x;  // 512
  const int h = bx >> 7, rem = bx & 127, cb = rem >> 3, db = rem & 7;
  const int c0 = cb * 64, d0 = db * 64;
  const int j = tid & 63, i0 = tid >> 6;
#pragma unroll
  for (int p = 0; p < 16; ++p) {
    const int i = p * 4 + i0;
    t[i * 65 + j] = em[(size_t)h * 524288 + (size_t)(c0 + i) * 512 + d0 + j] * invn[h * 1024 + c0 + i];
  }
  __syncthreads();
#pragma unroll
  for (int p = 0; p < 16; ++p) {
    const int i = p * 4 + i0;
    nT[(size_t)h * 524288 + (size_t)(d0 + i) * 1024 + c0 + j] = (f16)t[j * 65 + i];
  }
}

__global__ void finalize_k(const u64* __restrict__ cs, const u64* __restrict__ gs,
                           float* __restrict__ out) {
  const int lane = threadIdx.x;  // 64
  u64 c = cs[lane] + cs[lane + 64] + cs[lane + 128] + cs[lane + 192];
  u64 g = gs[lane];
#pragma unroll
  for (int o = 1; o < 64; o <<= 1) {
    c += __shfl_xor(c, o);
    g += __shfl_xor(g, o);
  }
  if (lane == 0) {
    const double commit = (double)c / 65536.0 / 67108864.0;
    const double ortho = (double)g / 16777216.0 / 4194304.0 - (1.0 / 1024.0);
    out[11927552] = (float)(commit + 0.8 * ortho);
  }
}

__global__ void ws_fail_k(float* out) {
  if (threadIdx.x == 0) out[11927552] = -777777.0f;  // sentinel: ws too small
}

// ---------------------------------------------------------------------------
extern "C" void kernel_launch(void* const* d_in, const int* in_sizes, int n_in,
                              void* d_out, int out_size, void* d_ws, size_t ws_size,
                              hipStream_t stream) {
  (void)in_sizes; (void)n_in; (void)out_size;
  const float* x = (const float*)d_in[0];
  const float* w_in = (const float*)d_in[1];
  const float* b_in = (const float*)d_in[2];
  const float* embed = (const float*)d_in[3];
  const float* w_out = (const float*)d_in[4];
  const float* b_out = (const float*)d_in[5];
  const float* w_lin = (const float*)d_in[6];
  const float* b_lin = (const float*)d_in[7];
  float* out = (float*)d_out;
  char* ws = (char*)d_ws;

  // fixed-size buffers
  constexpr size_t SZ_WIN = 2097152, SZ_EFT = 4194304, SZ_WOUT = 2097152;
  constexpr size_t SZ_EP = 4194304, SZ_WLIN = 1572864, SZ_NT = 4194304;
  constexpr size_t SZ_SMALL = 16384 + 16384 + 524288 + 2048 + 512;
  constexpr size_t FIXED = SZ_WIN * 2 + SZ_EFT + SZ_WOUT + SZ_EP + SZ_WLIN + SZ_NT + SZ_SMALL;

  // chunked buffers: x0 hi/lo = CH*1024 B each; f hi/lo = CH*4096 B each; cand = CH*2048 B
  int CH = 16384, shCH = 14;
  if (ws_size < FIXED + (size_t)CH * 12288 || (size_t)CH * 6144 < 33554432) {}
  if (ws_size < FIXED + (size_t)16384 * 12288) { CH = 8192; shCH = 13; }
  if (ws_size < FIXED + (size_t)CH * 12288) {
    ws_fail_k<<<1, 64, 0, stream>>>(out);
    return;
  }

  size_t off = 0;
  f16* x0h = (f16*)(ws + off); off += (size_t)CH * 1024;
  f16* x0l = (f16*)(ws + off); off += (size_t)CH * 1024;
  f16* fh = (f16*)(ws + off); off += (size_t)CH * 4096;
  f16* fl = (f16*)(ws + off); off += (size_t)CH * 4096;
  u64* cand = (u64*)(ws + off); off += (size_t)CH * 2048;
  f16* winh = (f16*)(ws + off); off += SZ_WIN;
  f16* winl = (f16*)(ws + off); off += SZ_WIN;
  f16* eft = (f16*)(ws + off); off += SZ_EFT;
  f16* wout = (f16*)(ws + off); off += SZ_WOUT;
  f16* Ep = (f16*)(ws + off); off += SZ_EP;
  f16* wlint = (f16*)(ws + off); off += SZ_WLIN;
  f16* nT = (f16*)(ws + off); off += SZ_NT;
  float* esq = (float*)(ws + off); off += 16384;
  float* invn = (float*)(ws + off); off += 16384;
  int* indw = (int*)(ws + off); off += 524288;
  u64* cslots = (u64*)(ws + off); off += 2048;
  u64* gslots = (u64*)(ws + off); off += 512;
  f16* qT = (f16*)ws;  // 32MB alias over x0/f after last rescore (>=48MB dead there)

  hipMemsetAsync((void*)cslots, 0, 2560, stream);

  prep_win<<<1024, 256, 0, stream>>>(w_in, winh, winl);
  prep_embed_k<<<1024, 256, 0, stream>>>(embed, eft, esq, invn);
  prep_normT<<<512, 256, 0, stream>>>(embed, invn, nT);
  prep_wout<<<512, 256, 0, stream>>>(w_out, wout);
  prep_wlin<<<384, 256, 0, stream>>>(w_lin, wlint);

  // Ep = embed @ w_out^T per head  (plain [4096][512])
  gemm2<1><<<128, 256, 0, stream>>>(eft, nullptr, wout, nullptr, 0, 16,
                                    Ep, nullptr, nullptr, nullptr, nullptr);
  // ortho: ||N_h^T N_h||_F^2
  gemm2<2><<<64, 256, 0, stream>>>(nT, nullptr, nT, nullptr, 0, 32,
                                   nullptr, nullptr, nullptr, nullptr, gslots);

  for (int c0 = 0; c0 < 32768; c0 += CH) {
    prep_x0<<<CH / 4, 256, 0, stream>>>(x, c0, x0h, x0l);
    // f = ((x-seq_last)@w_in^T + b_in), split-f16 3-pass, all heads
    gemm2<0><<<(CH / 128) * 16, 256, 0, stream>>>(x0h, x0l, winh, winl, CH, 16,
                                                  fh, fl, b_in, nullptr, nullptr);
    // screen: scores + margin candidates, all heads
    gemm2<3><<<(CH / 128) * 32, 256, 0, stream>>>(fh, nullptr, eft, nullptr, CH, 16,
                                                  cand, nullptr, nullptr, esq, nullptr);
    // exact rescore -> indices + commit d^2
    rescore_k<<<CH, 256, 0, stream>>>(cand, fh, fl, embed, c0, shCH,
                                      indw, out + 11796480, cslots);
  }

  quantize_qT<<<512, 256, 0, stream>>>(indw, Ep, b_out, qT);
  // y = w_lin @ quantized + b_lin + seq_last
  gemm2<4><<<768, 256, 0, stream>>>(wlint, nullptr, qT, nullptr, 0, 32,
                                    out, nullptr, b_lin, x, nullptr);
  finalize_k<<<1, 64, 0, stream>>>(cslots, gslots, out);
}

// Round 5
// 708.326 us; speedup vs baseline: 1.3215x; 1.0614x over previous
//
#include <hip/hip_runtime.h>
#include <stdint.h>

typedef unsigned int u32;
typedef unsigned long long u64;
typedef _Float16 f16;
typedef __attribute__((ext_vector_type(8))) _Float16 f16x8;
typedef __attribute__((ext_vector_type(4))) _Float16 f16x4;
typedef __attribute__((ext_vector_type(2))) _Float16 f16x2;
typedef __attribute__((ext_vector_type(4))) float f32x4;

#define MFMA16(a, b, c) __builtin_amdgcn_mfma_f32_16x16x32_f16((a), (b), (c), 0, 0, 0)
#define MARGIN 2.0f
#define WAITV(n) asm volatile("s_waitcnt vmcnt(" #n ")" ::: "memory")

__device__ __forceinline__ u32 ford(float x) { u32 u = __float_as_uint(x); return (u & 0x80000000u) ? ~u : (u | 0x80000000u); }
__device__ __forceinline__ float iford(u32 v) { u32 u = (v & 0x80000000u) ? (v & 0x7FFFFFFFu) : ~v; return __uint_as_float(u); }
__device__ __forceinline__ int xswz(int i, int n) { return (i & 7) * (n >> 3) + (i >> 3); }  // n%8==0

typedef __attribute__((address_space(1))) const unsigned char ga_t;
typedef __attribute__((address_space(3))) unsigned char la_t;
__device__ __forceinline__ void gl16(const void* g, void* l) {
  __builtin_amdgcn_global_load_lds((ga_t*)g, (la_t*)l, 16, 0, 0);
}

// Stage one 128-row x 32-col f16 k-tile (8KB) from plain row-major global into
// linear LDS, applying the inverse bank swizzle on the SOURCE address.
// LDS (r, s16B) holds global 16B-slot s ^ ((r>>1)&3). 2 gl16 per thread.
template <int LDK>
__device__ __forceinline__ void stg8k(const f16* gRowBase, int ktile, char* sdst, int tid) {
#pragma unroll
  for (int it = 0; it < 2; ++it) {
    const int u = (tid + (it << 8)) << 4;  // LDS byte offset in [0, 8192)
    const int r = u >> 6, s = (u >> 4) & 3;
    const char* src = (const char*)gRowBase + (size_t)r * (LDK * 2) + ((size_t)ktile << 6) +
                      (size_t)((s ^ ((r >> 1) & 3)) << 4);
    gl16(src, sdst + u);
  }
}

// ---------------------------------------------------------------------------
// NT-GEMM, plain row-major f16 operands, BM=BN=128, BK=32, 256 thr (4 waves),
// global_load_lds staging, D-deep circular LDS buffers, counted vmcnt + raw
// s_barrier (loads stay in flight across barriers).
// MODE 0 (K1): 3-pass split (A=x0 hi/lo, B=w_in hi/lo all heads); f16 hi/lo out.
// MODE 1 (Ep): out f16 plain.  MODE 2 (gram): sum(C^2) -> fixed-point atomic.
// MODE 3 (screen): score=esq-2S, per-row margin candidates, head-major grid.
// MODE 4 (y): out fp32 + b_lin[m] + seq_last[n].
// ---------------------------------------------------------------------------
template <int MODE>
__global__ __launch_bounds__(256, (MODE == 0 || MODE == 3) ? 2 : 3) void gemm2(
    const f16* __restrict__ Ah, const f16* __restrict__ Al,
    const f16* __restrict__ Bh, const f16* __restrict__ Bl,
    int chrows,
    void* __restrict__ out0, void* __restrict__ out1,
    const float* __restrict__ bias, const float* __restrict__ aux,
    u64* __restrict__ slots) {
  constexpr bool K1 = (MODE == 0);
  constexpr int LDK = (MODE == 2 || MODE == 4) ? 1024 : 512;
  constexpr int OPS = K1 ? 4 : 2;
  constexpr int D = K1 ? 2 : 3;
  constexpr int KT = (MODE == 2 || MODE == 4) ? 32 : 16;
  constexpr int BUF = OPS * 8192;
  constexpr int LDS_SZ = D * BUF + ((MODE == 3) ? 8704 : 0);
  __shared__ char lds[LDS_SZ];

  const int tid = threadIdx.x;
  const int lane = tid & 63, wid = tid >> 6;
  const int wm = wid >> 1, wn = wid & 1;

  int blkm, blkn, z = 0;
  {
    const int s = xswz(blockIdx.x, gridDim.x);
    if constexpr (MODE == 0) { blkn = s & 15; blkm = s >> 4; }
    else if constexpr (MODE == 1) { blkn = s & 3; blkm = s >> 2; z = blkm >> 3; }
    else if constexpr (MODE == 2) { blkn = s & 3; blkm = (s >> 2) & 3; z = s >> 4; }
    else if constexpr (MODE == 3) {
      const int bph = (chrows >> 7) << 3;  // bands per head * 8
      z = s / bph;                          // head
      const int rem = s - z * bph;
      blkm = rem >> 3; blkn = rem & 7;      // blkn = code col-block within head
    } else { const int r2 = s % 24; blkm = r2 % 6; blkn = r2 / 6; z = s / 24; }
  }

  if constexpr (MODE == 3) {
    u64* candL = (u64*)(lds + D * BUF);
    int* cntL = (int*)(lds + D * BUF + 8192);
    for (int i = tid; i < 1024; i += 256) candL[i] = ~0ull;
    if (tid < 128) cntL[tid] = 0;
  }

  // operand base pointers (128-row bands)
  const f16 *Ab, *Bb, *Alb = nullptr, *Blb = nullptr;
  if constexpr (MODE == 0) {
    Ab = Ah + (size_t)blkm * 65536;            // x0h [chrows][512]
    Alb = Al + (size_t)blkm * 65536;
    Bb = Bh + (size_t)blkn * 65536;            // winh [2048][512]
    Blb = Bl + (size_t)blkn * 65536;
  } else if constexpr (MODE == 1) {
    Ab = Ah + (size_t)blkm * 65536;            // eft [4096][512]
    Bb = Bh + (size_t)z * 262144 + (size_t)blkn * 65536;  // wout [4][512][512]
  } else if constexpr (MODE == 2) {
    Ab = Ah + (size_t)z * 524288 + (size_t)blkm * 131072;  // nT [4][512][1024]
    Bb = Bh + (size_t)z * 524288 + (size_t)blkn * 131072;
  } else if constexpr (MODE == 3) {
    Ab = Ah + ((size_t)z * chrows + (size_t)blkm * 128) * 512;  // fh head band
    Bb = Bh + (size_t)z * 524288 + (size_t)blkn * 65536;        // eft head cols
  } else {
    Ab = Ah + (size_t)blkm * 131072;           // wlin [768][1024]
    Bb = Bh + (size_t)z * 524288 + (size_t)blkn * 131072;  // qT [32][512][1024]
  }

  f32x4 acc[4][4];
#pragma unroll
  for (int i = 0; i < 4; ++i)
#pragma unroll
    for (int j = 0; j < 4; ++j) acc[i][j] = f32x4{0.f, 0.f, 0.f, 0.f};

  // prologue: stage k-tiles 0..D-2
#pragma unroll
  for (int d = 0; d < D - 1; ++d) {
    char* nb = lds + d * BUF;
    stg8k<LDK>(Ab, d, nb, tid);
    if constexpr (K1) stg8k<LDK>(Alb, d, nb + 8192, tid);
    stg8k<LDK>(Bb, d, nb + (K1 ? 16384 : 8192), tid);
    if constexpr (K1) stg8k<LDK>(Blb, d, nb + 24576, tid);
  }

#pragma unroll
  for (int kc = 0; kc < KT; ++kc) {
    if (kc + D - 1 < KT) {  // prefetch into buffer freed last iteration
      char* nb = lds + ((kc + D - 1) % D) * BUF;
      stg8k<LDK>(Ab, kc + D - 1, nb, tid);
      if constexpr (K1) stg8k<LDK>(Alb, kc + D - 1, nb + 8192, tid);
      stg8k<LDK>(Bb, kc + D - 1, nb + (K1 ? 16384 : 8192), tid);
      if constexpr (K1) stg8k<LDK>(Blb, kc + D - 1, nb + 24576, tid);
    }
    const int nf = KT - 1 - kc;  // future tiles
    if (nf >= D - 1) WAITV(8);           // (D-1)*loads: D2*8 or D3... both 8
    else if (D == 3 && nf == 1) WAITV(4);
    else WAITV(0);
    __builtin_amdgcn_s_barrier();  // raw: does NOT drain vmcnt
    const char* cbuf = lds + (kc % D) * BUF;
    f16x8 ah[4], al[4];
#pragma unroll
    for (int mt = 0; mt < 4; ++mt) {
      const int rr = wm * 64 + mt * 16 + (lane & 15);
      const int o = rr * 64 + (((lane >> 4) ^ ((rr >> 1) & 3)) << 4);
      ah[mt] = *(const f16x8*)(cbuf + o);
      if constexpr (K1) al[mt] = *(const f16x8*)(cbuf + 8192 + o);
    }
    __builtin_amdgcn_s_setprio(1);
#pragma unroll
    for (int nt = 0; nt < 4; ++nt) {
      const int rn = wn * 64 + nt * 16 + (lane & 15);
      const int o = rn * 64 + (((lane >> 4) ^ ((rn >> 1) & 3)) << 4);
      const f16x8 bh = *(const f16x8*)(cbuf + (K1 ? 16384 : 8192) + o);
      f16x8 bl;
      if constexpr (K1) bl = *(const f16x8*)(cbuf + 24576 + o);
#pragma unroll
      for (int mt = 0; mt < 4; ++mt) {
        if constexpr (K1) {
          acc[mt][nt] = MFMA16(al[mt], bh, acc[mt][nt]);
          acc[mt][nt] = MFMA16(ah[mt], bl, acc[mt][nt]);
        }
        acc[mt][nt] = MFMA16(ah[mt], bh, acc[mt][nt]);
      }
    }
    __builtin_amdgcn_s_setprio(0);
    __builtin_amdgcn_s_barrier();  // all waves done reading buf kc%D
  }

  // ---- epilogues ---- C/D: col = lane&15, row = (lane>>4)*4 + reg
  if constexpr (MODE == 0) {
    f16* fh = (f16*)out0;
    f16* fl = (f16*)out1;
#pragma unroll
    for (int nt = 0; nt < 4; ++nt) {
      const int gc = blkn * 128 + wn * 64 + nt * 16 + (lane & 15);
      const float bv = bias[gc];
      const int h = gc >> 9, d = gc & 511;
#pragma unroll
      for (int mt = 0; mt < 4; ++mt)
#pragma unroll
        for (int r = 0; r < 4; ++r) {
          const int grow = blkm * 128 + wm * 64 + mt * 16 + ((lane >> 4) << 2) + r;
          const float v = acc[mt][nt][r] * 6.103515625e-05f + bv;  // /16384 exact
          const f16 hv = (f16)v;
          const size_t off = ((size_t)h * chrows + grow) * 512 + d;
          fh[off] = hv;
          fl[off] = (f16)(v - (float)hv);
        }
    }
  } else if constexpr (MODE == 1) {
    f16* o = (f16*)out0;  // Ep [4096][512]
#pragma unroll
    for (int nt = 0; nt < 4; ++nt) {
      const int gc = blkn * 128 + wn * 64 + nt * 16 + (lane & 15);
#pragma unroll
      for (int mt = 0; mt < 4; ++mt)
#pragma unroll
        for (int r = 0; r < 4; ++r) {
          const size_t grow = (size_t)blkm * 128 + wm * 64 + mt * 16 + ((lane >> 4) << 2) + r;
          o[grow * 512 + gc] = (f16)acc[mt][nt][r];
        }
    }
  } else if constexpr (MODE == 2) {
    float ssum = 0.f;
#pragma unroll
    for (int mt = 0; mt < 4; ++mt)
#pragma unroll
      for (int nt = 0; nt < 4; ++nt)
#pragma unroll
        for (int r = 0; r < 4; ++r) ssum += acc[mt][nt][r] * acc[mt][nt][r];
#pragma unroll
    for (int o = 1; o < 64; o <<= 1) ssum += __shfl_xor(ssum, o);
    float* wp = (float*)lds;
    __syncthreads();
    if (lane == 0) wp[wid] = ssum;
    __syncthreads();
    if (tid == 0) {
      const float p = wp[0] + wp[1] + wp[2] + wp[3];
      atomicAdd(slots + (blockIdx.x & 63), (u64)llrintf(p * 16777216.f));
    }
  } else if constexpr (MODE == 3) {
    u64* candL = (u64*)(lds + D * BUF);
    int* cntL = (int*)(lds + D * BUF + 8192);
    u64* candG = (u64*)out0;
    const int h = z;
    float escol[4];
    int cc[4];
#pragma unroll
    for (int nt = 0; nt < 4; ++nt) {
      cc[nt] = blkn * 128 + wn * 64 + nt * 16 + (lane & 15);  // code idx in head
      escol[nt] = aux[h * 1024 + cc[nt]];
    }
#pragma unroll
    for (int mt = 0; mt < 4; ++mt)
#pragma unroll
      for (int r = 0; r < 4; ++r) {
        const int row_l = wm * 64 + mt * 16 + ((lane >> 4) << 2) + r;
        float vals[4];
        float mn = 3.4e38f;
#pragma unroll
        for (int nt = 0; nt < 4; ++nt) {
          const float v = escol[nt] - 2.0f * acc[mt][nt][r];
          vals[nt] = v;
          mn = fminf(mn, v);
        }
#pragma unroll
        for (int o = 1; o < 16; o <<= 1) mn = fminf(mn, __shfl_xor(mn, o));
        const float lim = mn + MARGIN;
#pragma unroll
        for (int nt = 0; nt < 4; ++nt)
          if (vals[nt] <= lim) {
            const int p = atomicAdd(&cntL[row_l], 1);
            if (p < 8) candL[(row_l << 3) + p] = ((u64)ford(vals[nt]) << 32) | (u32)cc[nt];
          }
      }
    __syncthreads();
#pragma unroll
    for (int j = 0; j < 4; ++j) {
      const int idx = tid * 4 + j;
      const int row_l = idx >> 3, slot = idx & 7;
      const size_t grow = (size_t)blkm * 128 + row_l;
      candG[((size_t)h * chrows + grow) * 64 + (size_t)blkn * 8 + slot] = candL[idx];
    }
  } else {  // MODE 4
    float* oy = (float*)out0 + (size_t)z * 368640;
    const float* xseq = aux + (size_t)z * 524288 + 523776;
    float sl[4];
    int gd[4];
#pragma unroll
    for (int nt = 0; nt < 4; ++nt) {
      gd[nt] = blkn * 128 + wn * 64 + nt * 16 + (lane & 15);
      sl[nt] = xseq[gd[nt]];
    }
#pragma unroll
    for (int mt = 0; mt < 4; ++mt)
#pragma unroll
      for (int r = 0; r < 4; ++r) {
        const int p = blkm * 128 + wm * 64 + mt * 16 + ((lane >> 4) << 2) + r;
        if (p < 720) {
          const float bp = bias[p];
#pragma unroll
          for (int nt = 0; nt < 4; ++nt) oy[(size_t)p * 512 + gd[nt]] = acc[mt][nt][r] + bp + sl[nt];
        }
      }
  }
}

// ---------------------------------------------------------------------------
// Rescore: exact fp64 distances (f = fh+fl vs fp32 embed) over margin set.
// ---------------------------------------------------------------------------
__global__ __launch_bounds__(256, 4) void rescore_k(
    const u64* __restrict__ candG, const f16* __restrict__ fh,
    const f16* __restrict__ fl, const float* __restrict__ embed,
    int n0, int shCH,
    int* __restrict__ indw, float* __restrict__ indout, u64* __restrict__ cslots) {
  const int tid = threadIdx.x, lane = tid & 63, wid = tid >> 6;
  const int r = blockIdx.x * 4 + wid;  // [0, 4*CH): r = h*CH + row
  const int h = r >> shCH, row = r & ((1 << shCH) - 1);
  u64 cu = candG[(size_t)r * 64 + lane];
  u64 mn = cu;
#pragma unroll
  for (int o = 1; o < 64; o <<= 1) { const u64 t = __shfl_xor(mn, o); if (t < mn) mn = t; }
  const float lim = iford((u32)(mn >> 32)) + MARGIN;
  const bool pass = iford((u32)(cu >> 32)) <= lim;  // empty slots -> NaN -> false
  u64 mask = __ballot(pass);
  float fv[8];
  {
    const size_t fo = (size_t)r * 512 + lane * 8;
    const f16x8 hv = *(const f16x8*)(fh + fo);
    const f16x8 lv = *(const f16x8*)(fl + fo);
#pragma unroll
    for (int j = 0; j < 8; ++j) fv[j] = (float)hv[j] + (float)lv[j];
  }
  double bestd = 1e300;
  int bestc = 0x7FFFFFFF;
  while (mask) {
    const int src = __ffsll((unsigned long long)mask) - 1;
    mask &= mask - 1;
    const int c = (int)(u32)__shfl(cu, src);
    const float* e = embed + ((size_t)h * 1024 + c) * 512 + lane * 8;
    const float4 e0 = *(const float4*)e, e1 = *(const float4*)(e + 4);
    const float ev[8] = {e0.x, e0.y, e0.z, e0.w, e1.x, e1.y, e1.z, e1.w};
    double sd = 0.0;
#pragma unroll
    for (int j = 0; j < 8; ++j) { const double d = (double)fv[j] - (double)ev[j]; sd += d * d; }
#pragma unroll
    for (int o = 1; o < 64; o <<= 1) sd += __shfl_xor(sd, o);
    if (sd < bestd || (sd == bestd && c < bestc)) { bestd = sd; bestc = c; }
  }
  if (lane == 0) {
    const int n = n0 + row;
    indw[(size_t)n * 4 + h] = bestc;
    indout[(size_t)n * 4 + h] = (float)bestc;
    atomicAdd(cslots + (blockIdx.x & 255), (u64)llrint(bestd * 65536.0));
  }
}

// quantized^T gather: qT[b][d][s] = f16( b_out[d] + sum_h Ep[h*1024+ind][d] )
__global__ __launch_bounds__(256) void quantize_qT(
    const int* __restrict__ indw, const f16* __restrict__ Ep,
    const float* __restrict__ b_out, f16* __restrict__ qT) {
  const int tid = threadIdx.x;
  const int b = blockIdx.x >> 4, s0 = (blockIdx.x & 15) << 6;
  __shared__ int inds[64][4];
  inds[tid >> 2][tid & 3] = indw[(size_t)(b * 1024 + s0 + (tid >> 2)) * 4 + (tid & 3)];
  __syncthreads();
  const int d0 = tid * 2;
  const float ba0 = b_out[d0], ba1 = b_out[d0 + 1];
  u32 r0[32], r1[32];
  f16 t0 = (f16)0.f, t1 = (f16)0.f;
#pragma unroll
  for (int ss = 0; ss < 64; ++ss) {
    float a0 = ba0, a1 = ba1;
#pragma unroll
    for (int h = 0; h < 4; ++h) {
      const int c = inds[ss][h];
      const f16x2 p = *(const f16x2*)(Ep + (((size_t)h * 1024 + c) * 512 + d0));
      a0 += (float)p[0];
      a1 += (float)p[1];
    }
    const f16 q0 = (f16)a0, q1 = (f16)a1;
    if (ss & 1) {
      f16x2 w0; w0[0] = t0; w0[1] = q0; __builtin_memcpy(&r0[ss >> 1], &w0, 4);
      f16x2 w1; w1[0] = t1; w1[1] = q1; __builtin_memcpy(&r1[ss >> 1], &w1, 4);
    } else { t0 = q0; t1 = q1; }
  }
  const size_t o0 = ((size_t)b * 512 + d0) * 1024 + s0;
#pragma unroll
  for (int i = 0; i < 8; ++i) {
    uint4 v; v.x = r0[4 * i]; v.y = r0[4 * i + 1]; v.z = r0[4 * i + 2]; v.w = r0[4 * i + 3];
    *(uint4*)(qT + o0 + (size_t)i * 8) = v;
  }
  const size_t o1 = o0 + 1024;
#pragma unroll
  for (int i = 0; i < 8; ++i) {
    uint4 v; v.x = r1[4 * i]; v.y = r1[4 * i + 1]; v.z = r1[4 * i + 2]; v.w = r1[4 * i + 3];
    *(uint4*)(qT + o1 + (size_t)i * 8) = v;
  }
}

// ---- prep kernels (all plain row-major outputs) ----
__global__ __launch_bounds__(256) void prep_x0(const float* __restrict__ x, int n0,
                                               f16* __restrict__ ht, f16* __restrict__ lt) {
  const int id = blockIdx.x * 256 + threadIdx.x;  // CH*64 groups of 8
  const int k8 = id & 63, r = id >> 6;
  const int n = n0 + r, b = n >> 10;
  const float* ap = x + (size_t)n * 512 + k8 * 8;
  const float* sp = x + (size_t)b * 524288 + 523776 + k8 * 8;
  const float4 a0 = *(const float4*)ap, a1 = *(const float4*)(ap + 4);
  const float4 s0 = *(const float4*)sp, s1 = *(const float4*)(sp + 4);
  const float v[8] = {(a0.x - s0.x) * 16.f, (a0.y - s0.y) * 16.f, (a0.z - s0.z) * 16.f,
                      (a0.w - s0.w) * 16.f, (a1.x - s1.x) * 16.f, (a1.y - s1.y) * 16.f,
                      (a1.z - s1.z) * 16.f, (a1.w - s1.w) * 16.f};
  f16x8 hv, lv;
#pragma unroll
  for (int j = 0; j < 8; ++j) { const f16 h = (f16)v[j]; hv[j] = h; lv[j] = (f16)(v[j] - (float)h); }
  const size_t off = (size_t)r * 512 + k8 * 8;
  *(f16x8*)(ht + off) = hv;
  *(f16x8*)(lt + off) = lv;
}

__global__ __launch_bounds__(256) void prep_win(const float* __restrict__ src,
                                                f16* __restrict__ hi, f16* __restrict__ lo) {
  const size_t e = ((size_t)blockIdx.x * 256 + threadIdx.x) * 4;  // 2048*512 elems
  const float4 v = *(const float4*)(src + e);
  const float w[4] = {v.x * 1024.f, v.y * 1024.f, v.z * 1024.f, v.w * 1024.f};
  f16x4 hv, lv;
#pragma unroll
  for (int j = 0; j < 4; ++j) { const f16 h = (f16)w[j]; hv[j] = h; lv[j] = (f16)(w[j] - (float)h); }
  *(f16x4*)(hi + e) = hv;
  *(f16x4*)(lo + e) = lv;
}

__global__ __launch_bounds__(256) void prep_embed_k(const float* __restrict__ em,
                                                    f16* __restrict__ ef,
                                                    float* __restrict__ esq,
                                                    float* __restrict__ invn) {
  const int tid = threadIdx.x, lane = tid & 63, wid = tid >> 6;
  const int row = blockIdx.x * 4 + wid;  // 0..4095 = h*1024+c
  const float* er = em + (size_t)row * 512 + lane * 8;
  const float4 a = *(const float4*)er, b = *(const float4*)(er + 4);
  f16x8 v;
  v[0] = (f16)a.x; v[1] = (f16)a.y; v[2] = (f16)a.z; v[3] = (f16)a.w;
  v[4] = (f16)b.x; v[5] = (f16)b.y; v[6] = (f16)b.z; v[7] = (f16)b.w;
  *(f16x8*)(ef + (size_t)row * 512 + lane * 8) = v;
  float s = a.x * a.x + a.y * a.y + a.z * a.z + a.w * a.w +
            b.x * b.x + b.y * b.y + b.z * b.z + b.w * b.w;
#pragma unroll
  for (int o = 1; o < 64; o <<= 1) s += __shfl_xor(s, o);
  if (lane == 0) { esq[row] = s; invn[row] = 1.0f / sqrtf(s); }
}

__global__ __launch_bounds__(256) void prep_wout(const float* __restrict__ src,
                                                 f16* __restrict__ dst) {
  const int id = blockIdx.x * 256 + threadIdx.x;  // 2048*64
  const int k8 = id & 63, rg = id >> 6;
  const int d = rg & 511, h = rg >> 9;
  const float* ap = src + (size_t)d * 2048 + h * 512 + k8 * 8;
  const float4 a0 = *(const float4*)ap, a1 = *(const float4*)(ap + 4);
  f16x8 v;
  v[0] = (f16)a0.x; v[1] = (f16)a0.y; v[2] = (f16)a0.z; v[3] = (f16)a0.w;
  v[4] = (f16)a1.x; v[5] = (f16)a1.y; v[6] = (f16)a1.z; v[7] = (f16)a1.w;
  *(f16x8*)(dst + (size_t)h * 262144 + (size_t)d * 512 + k8 * 8) = v;
}

__global__ __launch_bounds__(256) void prep_wlin(const float* __restrict__ src,
                                                 f16* __restrict__ dst) {
  const int id = blockIdx.x * 256 + threadIdx.x;  // 768*128
  const int k8 = id & 127, row = id >> 7;
  float4 a0 = {0.f, 0.f, 0.f, 0.f}, a1 = a0;
  if (row < 720) {
    const float* ap = src + (size_t)row * 1024 + k8 * 8;
    a0 = *(const float4*)ap;
    a1 = *(const float4*)(ap + 4);
  }
  f16x8 v;
  v[0] = (f16)a0.x; v[1] = (f16)a0.y; v[2] = (f16)a0.z; v[3] = (f16)a0.w;
  v[4] = (f16)a1.x; v[5] = (f16)a1.y; v[6] = (f16)a1.z; v[7] = (f16)a1.w;
  *(f16x8*)(dst + (size_t)row * 1024 + k8 * 8) = v;
}

__global__ __launch_bounds__(256) void prep_normT(const float* __restrict__ em,
                                                  const float* __restrict__ invn,
                                                  f16* __restrict__ nT) {
  __shared__ float t[64 * 65];
  const int tid = threadIdx.x;
  const int bx = blockIdx.x;  // 512
  const int h = bx >> 7, rem = bx & 127, cb = rem >> 3, db = rem & 7;
  const int c0 = cb * 64, d0 = db * 64;
  const int j = tid & 63, i0 = tid >> 6;
#pragma unroll
  for (int p = 0; p < 16; ++p) {
    const int i = p * 4 + i0;
    t[i * 65 + j] = em[(size_t)h * 524288 + (size_t)(c0 + i) * 512 + d0 + j] * invn[h * 1024 + c0 + i];
  }
  __syncthreads();
#pragma unroll
  for (int p = 0; p < 16; ++p) {
    const int i = p * 4 + i0;
    nT[(size_t)h * 524288 + (size_t)(d0 + i) * 1024 + c0 + j] = (f16)t[j * 65 + i];
  }
}

__global__ void finalize_k(const u64* __restrict__ cs, const u64* __restrict__ gs,
                           float* __restrict__ out) {
  const int lane = threadIdx.x;  // 64
  u64 c = cs[lane] + cs[lane + 64] + cs[lane + 128] + cs[lane + 192];
  u64 g = gs[lane];
#pragma unroll
  for (int o = 1; o < 64; o <<= 1) {
    c += __shfl_xor(c, o);
    g += __shfl_xor(g, o);
  }
  if (lane == 0) {
    const double commit = (double)c / 65536.0 / 67108864.0;
    const double ortho = (double)g / 16777216.0 / 4194304.0 - (1.0 / 1024.0);
    out[11927552] = (float)(commit + 0.8 * ortho);
  }
}

__global__ void ws_fail_k(float* out) {
  if (threadIdx.x == 0) out[11927552] = -777777.0f;  // sentinel: ws too small
}

// ---------------------------------------------------------------------------
extern "C" void kernel_launch(void* const* d_in, const int* in_sizes, int n_in,
                              void* d_out, int out_size, void* d_ws, size_t ws_size,
                              hipStream_t stream) {
  (void)in_sizes; (void)n_in; (void)out_size;
  const float* x = (const float*)d_in[0];
  const float* w_in = (const float*)d_in[1];
  const float* b_in = (const float*)d_in[2];
  const float* embed = (const float*)d_in[3];
  const float* w_out = (const float*)d_in[4];
  const float* b_out = (const float*)d_in[5];
  const float* w_lin = (const float*)d_in[6];
  const float* b_lin = (const float*)d_in[7];
  float* out = (float*)d_out;
  char* ws = (char*)d_ws;

  constexpr size_t SZ_WIN = 2097152, SZ_EFT = 4194304, SZ_WOUT = 2097152;
  constexpr size_t SZ_EP = 4194304, SZ_WLIN = 1572864, SZ_NT = 4194304;
  constexpr size_t SZ_SMALL = 16384 + 16384 + 524288 + 2048 + 512;
  constexpr size_t FIXED = SZ_WIN * 2 + SZ_EFT + SZ_WOUT + SZ_EP + SZ_WLIN + SZ_NT + SZ_SMALL;

  int CH = 16384, shCH = 14;
  if (ws_size < FIXED + (size_t)16384 * 12288) { CH = 8192; shCH = 13; }
  if (ws_size < FIXED + (size_t)CH * 12288) {
    ws_fail_k<<<1, 64, 0, stream>>>(out);
    return;
  }

  size_t off = 0;
  f16* x0h = (f16*)(ws + off); off += (size_t)CH * 1024;
  f16* x0l = (f16*)(ws + off); off += (size_t)CH * 1024;
  f16* fh = (f16*)(ws + off); off += (size_t)CH * 4096;
  f16* fl = (f16*)(ws + off); off += (size_t)CH * 4096;
  u64* cand = (u64*)(ws + off); off += (size_t)CH * 2048;
  f16* winh = (f16*)(ws + off); off += SZ_WIN;
  f16* winl = (f16*)(ws + off); off += SZ_WIN;
  f16* eft = (f16*)(ws + off); off += SZ_EFT;
  f16* wout = (f16*)(ws + off); off += SZ_WOUT;
  f16* Ep = (f16*)(ws + off); off += SZ_EP;
  f16* wlint = (f16*)(ws + off); off += SZ_WLIN;
  f16* nT = (f16*)(ws + off); off += SZ_NT;
  float* esq = (float*)(ws + off); off += 16384;
  float* invn = (float*)(ws + off); off += 16384;
  int* indw = (int*)(ws + off); off += 524288;
  u64* cslots = (u64*)(ws + off); off += 2048;
  u64* gslots = (u64*)(ws + off); off += 512;
  f16* qT = (f16*)ws;  // 32MB alias over x0/f after last rescore

  hipMemsetAsync((void*)cslots, 0, 2560, stream);

  prep_win<<<1024, 256, 0, stream>>>(w_in, winh, winl);
  prep_embed_k<<<1024, 256, 0, stream>>>(embed, eft, esq, invn);
  prep_normT<<<512, 256, 0, stream>>>(embed, invn, nT);
  prep_wout<<<512, 256, 0, stream>>>(w_out, wout);
  prep_wlin<<<384, 256, 0, stream>>>(w_lin, wlint);

  // Ep = embed @ w_out^T per head  (plain [4096][512])
  gemm2<1><<<128, 256, 0, stream>>>(eft, nullptr, wout, nullptr, 0,
                                    Ep, nullptr, nullptr, nullptr, nullptr);
  // ortho: ||N_h^T N_h||_F^2
  gemm2<2><<<64, 256, 0, stream>>>(nT, nullptr, nT, nullptr, 0,
                                   nullptr, nullptr, nullptr, nullptr, gslots);

  for (int c0 = 0; c0 < 32768; c0 += CH) {
    prep_x0<<<CH / 4, 256, 0, stream>>>(x, c0, x0h, x0l);
    // f = ((x-seq_last)@w_in^T + b_in), split-f16 3-pass, all heads
    gemm2<0><<<(CH / 128) * 16, 256, 0, stream>>>(x0h, x0l, winh, winl, CH,
                                                  fh, fl, b_in, nullptr, nullptr);
    // screen: scores + margin candidates (head-major L2 mapping)
    gemm2<3><<<(CH / 128) * 32, 256, 0, stream>>>(fh, nullptr, eft, nullptr, CH,
                                                  cand, nullptr, nullptr, esq, nullptr);
    // exact rescore -> indices + commit d^2
    rescore_k<<<CH, 256, 0, stream>>>(cand, fh, fl, embed, c0, shCH,
                                      indw, out + 11796480, cslots);
  }

  quantize_qT<<<512, 256, 0, stream>>>(indw, Ep, b_out, qT);
  // y = w_lin @ quantized + b_lin + seq_last
  gemm2<4><<<768, 256, 0, stream>>>(wlint, nullptr, qT, nullptr, 0,
                                    out, nullptr, b_lin, x, nullptr);
  finalize_k<<<1, 64, 0, stream>>>(cslots, gslots, out);
}

// Round 6
// 698.679 us; speedup vs baseline: 1.3397x; 1.0138x over previous
//
#include <hip/hip_runtime.h>
#include <stdint.h>

typedef unsigned int u32;
typedef unsigned long long u64;
typedef _Float16 f16;
typedef __attribute__((ext_vector_type(8))) _Float16 f16x8;
typedef __attribute__((ext_vector_type(4))) _Float16 f16x4;
typedef __attribute__((ext_vector_type(2))) _Float16 f16x2;
typedef __attribute__((ext_vector_type(4))) float f32x4;

#define MFMA16(a, b, c) __builtin_amdgcn_mfma_f32_16x16x32_f16((a), (b), (c), 0, 0, 0)
#define MARGIN 2.0f
#define WAITV(n) asm volatile("s_waitcnt vmcnt(" #n ")" ::: "memory")

__device__ __forceinline__ u32 ford(float x) { u32 u = __float_as_uint(x); return (u & 0x80000000u) ? ~u : (u | 0x80000000u); }
__device__ __forceinline__ float iford(u32 v) { u32 u = (v & 0x80000000u) ? (v & 0x7FFFFFFFu) : ~v; return __uint_as_float(u); }
__device__ __forceinline__ int xswz(int i, int n) { return (i & 7) * (n >> 3) + (i >> 3); }  // n%8==0

typedef __attribute__((address_space(1))) const unsigned char ga_t;
typedef __attribute__((address_space(3))) unsigned char la_t;
__device__ __forceinline__ void gl16(const void* g, void* l) {
  __builtin_amdgcn_global_load_lds((ga_t*)g, (la_t*)l, 16, 0, 0);
}

// Stage one 128-row x 32-col f16 k-tile (8KB) from plain row-major global into
// linear LDS, applying the inverse bank swizzle on the SOURCE address.
// LDS (r, s16B) holds global 16B-slot s ^ ((r>>1)&3). 2 gl16 per thread.
template <int LDK>
__device__ __forceinline__ void stg8k(const f16* gRowBase, int ktile, char* sdst, int tid) {
#pragma unroll
  for (int it = 0; it < 2; ++it) {
    const int u = (tid + (it << 8)) << 4;  // LDS byte offset in [0, 8192)
    const int r = u >> 6, s = (u >> 4) & 3;
    const char* src = (const char*)gRowBase + (size_t)r * (LDK * 2) + ((size_t)ktile << 6) +
                      (size_t)((s ^ ((r >> 1) & 3)) << 4);
    gl16(src, sdst + u);
  }
}

// ---------------------------------------------------------------------------
// NT-GEMM, plain row-major f16 operands, BK=32, global_load_lds staging,
// D-deep circular LDS buffers, counted vmcnt + raw s_barrier.
// MODE 0 (K1): BM=BN=128; 3-pass split (x0 hi/lo, w_in hi/lo); f16 hi/lo out.
// MODE 1 (Ep): 128x128, out f16.  MODE 2 (gram): 128x128, sum(C^2) atomic.
// MODE 3 (screen): BM=256, BN=128, waves 128x64; sparse candidates to global.
// MODE 4 (y): 128x128, out fp32 + b_lin[m] + seq_last[n].
// ---------------------------------------------------------------------------
template <int MODE>
__global__ __launch_bounds__(256, (MODE == 0 || MODE == 3) ? 2 : 3) void gemm2(
    const f16* __restrict__ Ah, const f16* __restrict__ Al,
    const f16* __restrict__ Bh, const f16* __restrict__ Bl,
    int chrows,
    void* __restrict__ out0, void* __restrict__ out1,
    const float* __restrict__ bias, const float* __restrict__ aux,
    u64* __restrict__ slots) {
  constexpr bool K1 = (MODE == 0);
  constexpr bool SC = (MODE == 3);
  constexpr int LDK = (MODE == 2 || MODE == 4) ? 1024 : 512;
  constexpr int D = K1 ? 2 : 3;
  constexpr int KT = (MODE == 2 || MODE == 4) ? 32 : 16;
  constexpr int MT = SC ? 8 : 4;
  constexpr int BUF = K1 ? 32768 : (SC ? 24576 : 16384);
  constexpr int LDS_SZ = D * BUF + (SC ? 1024 : 0);
  __shared__ char lds[LDS_SZ];

  const int tid = threadIdx.x;
  const int lane = tid & 63, wid = tid >> 6;
  const int wm = wid >> 1, wn = wid & 1;

  int blkm, blkn, z = 0;
  {
    const int s = xswz(blockIdx.x, gridDim.x);
    if constexpr (MODE == 0) { blkn = s & 15; blkm = s >> 4; }
    else if constexpr (MODE == 1) { blkn = s & 3; blkm = s >> 2; z = blkm >> 3; }
    else if constexpr (MODE == 2) { blkn = s & 3; blkm = (s >> 2) & 3; z = s >> 4; }
    else if constexpr (MODE == 3) {
      const int bph = (chrows >> 8) << 3;  // m-bands(256) per head * 8
      z = s / bph;
      const int rem = s - z * bph;
      blkm = rem >> 3; blkn = rem & 7;
    } else { const int r2 = s % 24; blkm = r2 % 6; blkn = r2 / 6; z = s / 24; }
  }

  int* cntL = (int*)(lds + D * BUF);
  if constexpr (SC) cntL[tid] = 0;

  // operand base pointers
  const f16 *Ab, *Bb, *Alb = nullptr, *Blb = nullptr;
  if constexpr (MODE == 0) {
    Ab = Ah + (size_t)blkm * 65536;            // x0h [chrows][512]
    Alb = Al + (size_t)blkm * 65536;
    Bb = Bh + (size_t)blkn * 65536;            // winh [2048][512]
    Blb = Bl + (size_t)blkn * 65536;
  } else if constexpr (MODE == 1) {
    Ab = Ah + (size_t)blkm * 65536;            // eft [4096][512]
    Bb = Bh + (size_t)z * 262144 + (size_t)blkn * 65536;  // wout [4][512][512]
  } else if constexpr (MODE == 2) {
    Ab = Ah + (size_t)z * 524288 + (size_t)blkm * 131072;  // nT [4][512][1024]
    Bb = Bh + (size_t)z * 524288 + (size_t)blkn * 131072;
  } else if constexpr (MODE == 3) {
    Ab = Ah + ((size_t)z * chrows + (size_t)blkm * 256) * 512;  // fh head band (256 rows)
    Bb = Bh + (size_t)z * 524288 + (size_t)blkn * 65536;        // eft head cols (128)
  } else {
    Ab = Ah + (size_t)blkm * 131072;           // wlin [768][1024]
    Bb = Bh + (size_t)z * 524288 + (size_t)blkn * 131072;  // qT [32][512][1024]
  }

  f32x4 acc[MT][4];
#pragma unroll
  for (int i = 0; i < MT; ++i)
#pragma unroll
    for (int j = 0; j < 4; ++j) acc[i][j] = f32x4{0.f, 0.f, 0.f, 0.f};

  // stage one k-tile into buffer nb
  auto stage = [&](int kt, char* nb) {
    stg8k<LDK>(Ab, kt, nb, tid);
    if constexpr (SC) stg8k<LDK>(Ab + 65536, kt, nb + 8192, tid);  // rows 128-255
    if constexpr (K1) stg8k<LDK>(Alb, kt, nb + 8192, tid);
    stg8k<LDK>(Bb, kt, nb + 16384 - (SC || K1 ? 0 : 8192), tid);
    if constexpr (K1) stg8k<LDK>(Blb, kt, nb + 24576, tid);
  };

#pragma unroll
  for (int d = 0; d < D - 1; ++d) stage(d, lds + d * BUF);

#pragma unroll
  for (int kc = 0; kc < KT; ++kc) {
    if (kc + D - 1 < KT) stage(kc + D - 1, lds + ((kc + D - 1) % D) * BUF);
    const int nf = KT - 1 - kc;  // future tiles staged beyond kc
    if constexpr (SC) {
      if (nf >= 2) WAITV(12);
      else if (nf == 1) WAITV(6);
      else WAITV(0);
    } else if constexpr (K1) {
      if (nf >= 1) WAITV(8);
      else WAITV(0);
    } else {
      if (nf >= 2) WAITV(8);
      else if (nf == 1) WAITV(4);
      else WAITV(0);
    }
    __builtin_amdgcn_s_barrier();  // raw: does NOT drain vmcnt
    const char* cbuf = lds + (kc % D) * BUF;
    f16x8 ah[MT], al[4];
#pragma unroll
    for (int mt = 0; mt < MT; ++mt) {
      const int rr = wm * (MT * 16) + mt * 16 + (lane & 15);
      const int o = rr * 64 + (((lane >> 4) ^ ((rr >> 1) & 3)) << 4);
      ah[mt] = *(const f16x8*)(cbuf + o);
      if constexpr (K1) al[mt] = *(const f16x8*)(cbuf + 8192 + o);
    }
    __builtin_amdgcn_s_setprio(1);
#pragma unroll
    for (int nt = 0; nt < 4; ++nt) {
      const int rn = wn * 64 + nt * 16 + (lane & 15);
      const int o = rn * 64 + (((lane >> 4) ^ ((rn >> 1) & 3)) << 4);
      const f16x8 bh = *(const f16x8*)(cbuf + (K1 || SC ? 16384 : 8192) + o);
      f16x8 bl;
      if constexpr (K1) bl = *(const f16x8*)(cbuf + 24576 + o);
#pragma unroll
      for (int mt = 0; mt < MT; ++mt) {
        if constexpr (K1) {
          acc[mt][nt] = MFMA16(al[mt], bh, acc[mt][nt]);
          acc[mt][nt] = MFMA16(ah[mt], bl, acc[mt][nt]);
        }
        acc[mt][nt] = MFMA16(ah[mt], bh, acc[mt][nt]);
      }
    }
    __builtin_amdgcn_s_setprio(0);
    __builtin_amdgcn_s_barrier();  // all waves done reading buf kc%D
  }

  // ---- epilogues ---- C/D: col = lane&15, row = (lane>>4)*4 + reg
  if constexpr (MODE == 0) {
    f16* fh = (f16*)out0;
    f16* fl = (f16*)out1;
#pragma unroll
    for (int nt = 0; nt < 4; ++nt) {
      const int gc = blkn * 128 + wn * 64 + nt * 16 + (lane & 15);
      const float bv = bias[gc];
      const int h = gc >> 9, d = gc & 511;
#pragma unroll
      for (int mt = 0; mt < 4; ++mt)
#pragma unroll
        for (int r = 0; r < 4; ++r) {
          const int grow = blkm * 128 + wm * 64 + mt * 16 + ((lane >> 4) << 2) + r;
          const float v = acc[mt][nt][r] * 6.103515625e-05f + bv;  // /16384 exact
          const f16 hv = (f16)v;
          const size_t off = ((size_t)h * chrows + grow) * 512 + d;
          fh[off] = hv;
          fl[off] = (f16)(v - (float)hv);
        }
    }
  } else if constexpr (MODE == 1) {
    f16* o = (f16*)out0;  // Ep [4096][512]
#pragma unroll
    for (int nt = 0; nt < 4; ++nt) {
      const int gc = blkn * 128 + wn * 64 + nt * 16 + (lane & 15);
#pragma unroll
      for (int mt = 0; mt < 4; ++mt)
#pragma unroll
        for (int r = 0; r < 4; ++r) {
          const size_t grow = (size_t)blkm * 128 + wm * 64 + mt * 16 + ((lane >> 4) << 2) + r;
          o[grow * 512 + gc] = (f16)acc[mt][nt][r];
        }
    }
  } else if constexpr (MODE == 2) {
    float ssum = 0.f;
#pragma unroll
    for (int mt = 0; mt < 4; ++mt)
#pragma unroll
      for (int nt = 0; nt < 4; ++nt)
#pragma unroll
        for (int r = 0; r < 4; ++r) ssum += acc[mt][nt][r] * acc[mt][nt][r];
#pragma unroll
    for (int o = 1; o < 64; o <<= 1) ssum += __shfl_xor(ssum, o);
    float* wp = (float*)lds;
    __syncthreads();
    if (lane == 0) wp[wid] = ssum;
    __syncthreads();
    if (tid == 0) {
      const float p = wp[0] + wp[1] + wp[2] + wp[3];
      atomicAdd(slots + (blockIdx.x & 63), (u64)llrintf(p * 16777216.f));
    }
  } else if constexpr (MODE == 3) {
    u64* candG = (u64*)out0;
    const int h = z;
    float escol[4];
    int cc[4];
#pragma unroll
    for (int nt = 0; nt < 4; ++nt) {
      cc[nt] = blkn * 128 + wn * 64 + nt * 16 + (lane & 15);  // code idx in head
      escol[nt] = aux[h * 1024 + cc[nt]];
    }
#pragma unroll
    for (int mt = 0; mt < 8; ++mt)
#pragma unroll
      for (int r = 0; r < 4; ++r) {
        const int row_l = wm * 128 + mt * 16 + ((lane >> 4) << 2) + r;  // [0,256)
        float vals[4];
        float mn = 3.4e38f;
#pragma unroll
        for (int nt = 0; nt < 4; ++nt) {
          const float v = escol[nt] - 2.0f * acc[mt][nt][r];
          vals[nt] = v;
          mn = fminf(mn, v);
        }
#pragma unroll
        for (int o = 1; o < 16; o <<= 1) mn = fminf(mn, __shfl_xor(mn, o));
        const float lim = mn + MARGIN;
#pragma unroll
        for (int nt = 0; nt < 4; ++nt)
          if (vals[nt] <= lim) {
            const int p = atomicAdd(&cntL[row_l], 1);
            if (p < 8) {
              const size_t grow = (size_t)blkm * 256 + row_l;
              candG[(((size_t)h * chrows + grow) * 8 + blkn) * 8 + p] =
                  ((u64)ford(vals[nt]) << 32) | (u32)cc[nt];
            }
          }
      }
  } else {  // MODE 4
    float* oy = (float*)out0 + (size_t)z * 368640;
    const float* xseq = aux + (size_t)z * 524288 + 523776;
    float sl[4];
    int gd[4];
#pragma unroll
    for (int nt = 0; nt < 4; ++nt) {
      gd[nt] = blkn * 128 + wn * 64 + nt * 16 + (lane & 15);
      sl[nt] = xseq[gd[nt]];
    }
#pragma unroll
    for (int mt = 0; mt < 4; ++mt)
#pragma unroll
      for (int r = 0; r < 4; ++r) {
        const int p = blkm * 128 + wm * 64 + mt * 16 + ((lane >> 4) << 2) + r;
        if (p < 720) {
          const float bp = bias[p];
#pragma unroll
          for (int nt = 0; nt < 4; ++nt) oy[(size_t)p * 512 + gd[nt]] = acc[mt][nt][r] + bp + sl[nt];
        }
      }
  }
}

// ---------------------------------------------------------------------------
// Rescore: exact fp64 distances (f = fh+fl vs fp32 embed) over margin set.
// ---------------------------------------------------------------------------
__global__ __launch_bounds__(256, 4) void rescore_k(
    const u64* __restrict__ candG, const f16* __restrict__ fh,
    const f16* __restrict__ fl, const float* __restrict__ embed,
    int n0, int shCH,
    int* __restrict__ indw, float* __restrict__ indout, u64* __restrict__ cslots) {
  const int tid = threadIdx.x, lane = tid & 63, wid = tid >> 6;
  const int r = blockIdx.x * 4 + wid;  // [0, 4*CH): r = h*CH + row
  const int h = r >> shCH, row = r & ((1 << shCH) - 1);
  u64 cu = candG[(size_t)r * 64 + lane];
  u64 mn = cu;
#pragma unroll
  for (int o = 1; o < 64; o <<= 1) { const u64 t = __shfl_xor(mn, o); if (t < mn) mn = t; }
  const float lim = iford((u32)(mn >> 32)) + MARGIN;
  const bool pass = iford((u32)(cu >> 32)) <= lim;  // empty slots -> NaN -> false
  u64 mask = __ballot(pass);
  float fv[8];
  {
    const size_t fo = (size_t)r * 512 + lane * 8;
    const f16x8 hv = *(const f16x8*)(fh + fo);
    const f16x8 lv = *(const f16x8*)(fl + fo);
#pragma unroll
    for (int j = 0; j < 8; ++j) fv[j] = (float)hv[j] + (float)lv[j];
  }
  double bestd = 1e300;
  int bestc = 0x7FFFFFFF;
  while (mask) {
    const int src = __ffsll((unsigned long long)mask) - 1;
    mask &= mask - 1;
    const int c = (int)(u32)__shfl(cu, src);
    const float* e = embed + ((size_t)h * 1024 + c) * 512 + lane * 8;
    const float4 e0 = *(const float4*)e, e1 = *(const float4*)(e + 4);
    const float ev[8] = {e0.x, e0.y, e0.z, e0.w, e1.x, e1.y, e1.z, e1.w};
    double sd = 0.0;
#pragma unroll
    for (int j = 0; j < 8; ++j) { const double d = (double)fv[j] - (double)ev[j]; sd += d * d; }
#pragma unroll
    for (int o = 1; o < 64; o <<= 1) sd += __shfl_xor(sd, o);
    if (sd < bestd || (sd == bestd && c < bestc)) { bestd = sd; bestc = c; }
  }
  if (lane == 0) {
    const int n = n0 + row;
    indw[(size_t)n * 4 + h] = bestc;
    indout[(size_t)n * 4 + h] = (float)bestc;
    atomicAdd(cslots + (blockIdx.x & 255), (u64)llrint(bestd * 65536.0));
  }
}

// quantized^T gather: qT[b][d][s] = f16( b_out[d] + sum_h Ep[h*1024+ind][d] )
__global__ __launch_bounds__(256) void quantize_qT(
    const int* __restrict__ indw, const f16* __restrict__ Ep,
    const float* __restrict__ b_out, f16* __restrict__ qT) {
  const int tid = threadIdx.x;
  const int b = blockIdx.x >> 4, s0 = (blockIdx.x & 15) << 6;
  __shared__ int inds[64][4];
  inds[tid >> 2][tid & 3] = indw[(size_t)(b * 1024 + s0 + (tid >> 2)) * 4 + (tid & 3)];
  __syncthreads();
  const int d0 = tid * 2;
  const float ba0 = b_out[d0], ba1 = b_out[d0 + 1];
  u32 r0[32], r1[32];
  f16 t0 = (f16)0.f, t1 = (f16)0.f;
#pragma unroll
  for (int ss = 0; ss < 64; ++ss) {
    float a0 = ba0, a1 = ba1;
#pragma unroll
    for (int h = 0; h < 4; ++h) {
      const int c = inds[ss][h];
      const f16x2 p = *(const f16x2*)(Ep + (((size_t)h * 1024 + c) * 512 + d0));
      a0 += (float)p[0];
      a1 += (float)p[1];
    }
    const f16 q0 = (f16)a0, q1 = (f16)a1;
    if (ss & 1) {
      f16x2 w0; w0[0] = t0; w0[1] = q0; __builtin_memcpy(&r0[ss >> 1], &w0, 4);
      f16x2 w1; w1[0] = t1; w1[1] = q1; __builtin_memcpy(&r1[ss >> 1], &w1, 4);
    } else { t0 = q0; t1 = q1; }
  }
  const size_t o0 = ((size_t)b * 512 + d0) * 1024 + s0;
#pragma unroll
  for (int i = 0; i < 8; ++i) {
    uint4 v; v.x = r0[4 * i]; v.y = r0[4 * i + 1]; v.z = r0[4 * i + 2]; v.w = r0[4 * i + 3];
    *(uint4*)(qT + o0 + (size_t)i * 8) = v;
  }
  const size_t o1 = o0 + 1024;
#pragma unroll
  for (int i = 0; i < 8; ++i) {
    uint4 v; v.x = r1[4 * i]; v.y = r1[4 * i + 1]; v.z = r1[4 * i + 2]; v.w = r1[4 * i + 3];
    *(uint4*)(qT + o1 + (size_t)i * 8) = v;
  }
}

// ---- prep kernels (all plain row-major outputs) ----
__global__ __launch_bounds__(256) void prep_x0(const float* __restrict__ x, int n0,
                                               f16* __restrict__ ht, f16* __restrict__ lt) {
  const int id = blockIdx.x * 256 + threadIdx.x;  // CH*64 groups of 8
  const int k8 = id & 63, r = id >> 6;
  const int n = n0 + r, b = n >> 10;
  const float* ap = x + (size_t)n * 512 + k8 * 8;
  const float* sp = x + (size_t)b * 524288 + 523776 + k8 * 8;
  const float4 a0 = *(const float4*)ap, a1 = *(const float4*)(ap + 4);
  const float4 s0 = *(const float4*)sp, s1 = *(const float4*)(sp + 4);
  const float v[8] = {(a0.x - s0.x) * 16.f, (a0.y - s0.y) * 16.f, (a0.z - s0.z) * 16.f,
                      (a0.w - s0.w) * 16.f, (a1.x - s1.x) * 16.f, (a1.y - s1.y) * 16.f,
                      (a1.z - s1.z) * 16.f, (a1.w - s1.w) * 16.f};
  f16x8 hv, lv;
#pragma unroll
  for (int j = 0; j < 8; ++j) { const f16 h = (f16)v[j]; hv[j] = h; lv[j] = (f16)(v[j] - (float)h); }
  const size_t off = (size_t)r * 512 + k8 * 8;
  *(f16x8*)(ht + off) = hv;
  *(f16x8*)(lt + off) = lv;
}

__global__ __launch_bounds__(256) void prep_win(const float* __restrict__ src,
                                                f16* __restrict__ hi, f16* __restrict__ lo) {
  const size_t e = ((size_t)blockIdx.x * 256 + threadIdx.x) * 4;  // 2048*512 elems
  const float4 v = *(const float4*)(src + e);
  const float w[4] = {v.x * 1024.f, v.y * 1024.f, v.z * 1024.f, v.w * 1024.f};
  f16x4 hv, lv;
#pragma unroll
  for (int j = 0; j < 4; ++j) { const f16 h = (f16)w[j]; hv[j] = h; lv[j] = (f16)(w[j] - (float)h); }
  *(f16x4*)(hi + e) = hv;
  *(f16x4*)(lo + e) = lv;
}

__global__ __launch_bounds__(256) void prep_embed_k(const float* __restrict__ em,
                                                    f16* __restrict__ ef,
                                                    float* __restrict__ esq,
                                                    float* __restrict__ invn) {
  const int tid = threadIdx.x, lane = tid & 63, wid = tid >> 6;
  const int row = blockIdx.x * 4 + wid;  // 0..4095 = h*1024+c
  const float* er = em + (size_t)row * 512 + lane * 8;
  const float4 a = *(const float4*)er, b = *(const float4*)(er + 4);
  f16x8 v;
  v[0] = (f16)a.x; v[1] = (f16)a.y; v[2] = (f16)a.z; v[3] = (f16)a.w;
  v[4] = (f16)b.x; v[5] = (f16)b.y; v[6] = (f16)b.z; v[7] = (f16)b.w;
  *(f16x8*)(ef + (size_t)row * 512 + lane * 8) = v;
  float s = a.x * a.x + a.y * a.y + a.z * a.z + a.w * a.w +
            b.x * b.x + b.y * b.y + b.z * b.z + b.w * b.w;
#pragma unroll
  for (int o = 1; o < 64; o <<= 1) s += __shfl_xor(s, o);
  if (lane == 0) { esq[row] = s; invn[row] = 1.0f / sqrtf(s); }
}

__global__ __launch_bounds__(256) void prep_wout(const float* __restrict__ src,
                                                 f16* __restrict__ dst) {
  const int id = blockIdx.x * 256 + threadIdx.x;  // 2048*64
  const int k8 = id & 63, rg = id >> 6;
  const int d = rg & 511, h = rg >> 9;
  const float* ap = src + (size_t)d * 2048 + h * 512 + k8 * 8;
  const float4 a0 = *(const float4*)ap, a1 = *(const float4*)(ap + 4);
  f16x8 v;
  v[0] = (f16)a0.x; v[1] = (f16)a0.y; v[2] = (f16)a0.z; v[3] = (f16)a0.w;
  v[4] = (f16)a1.x; v[5] = (f16)a1.y; v[6] = (f16)a1.z; v[7] = (f16)a1.w;
  *(f16x8*)(dst + (size_t)h * 262144 + (size_t)d * 512 + k8 * 8) = v;
}

__global__ __launch_bounds__(256) void prep_wlin(const float* __restrict__ src,
                                                 f16* __restrict__ dst) {
  const int id = blockIdx.x * 256 + threadIdx.x;  // 768*128
  const int k8 = id & 127, row = id >> 7;
  float4 a0 = {0.f, 0.f, 0.f, 0.f}, a1 = a0;
  if (row < 720) {
    const float* ap = src + (size_t)row * 1024 + k8 * 8;
    a0 = *(const float4*)ap;
    a1 = *(const float4*)(ap + 4);
  }
  f16x8 v;
  v[0] = (f16)a0.x; v[1] = (f16)a0.y; v[2] = (f16)a0.z; v[3] = (f16)a0.w;
  v[4] = (f16)a1.x; v[5] = (f16)a1.y; v[6] = (f16)a1.z; v[7] = (f16)a1.w;
  *(f16x8*)(dst + (size_t)row * 1024 + k8 * 8) = v;
}

__global__ __launch_bounds__(256) void prep_normT(const float* __restrict__ em,
                                                  const float* __restrict__ invn,
                                                  f16* __restrict__ nT) {
  __shared__ float t[64 * 65];
  const int tid = threadIdx.x;
  const int bx = blockIdx.x;  // 512
  const int h = bx >> 7, rem = bx & 127, cb = rem >> 3, db = rem & 7;
  const int c0 = cb * 64, d0 = db * 64;
  const int j = tid & 63, i0 = tid >> 6;
#pragma unroll
  for (int p = 0; p < 16; ++p) {
    const int i = p * 4 + i0;
    t[i * 65 + j] = em[(size_t)h * 524288 + (size_t)(c0 + i) * 512 + d0 + j] * invn[h * 1024 + c0 + i];
  }
  __syncthreads();
#pragma unroll
  for (int p = 0; p < 16; ++p) {
    const int i = p * 4 + i0;
    nT[(size_t)h * 524288 + (size_t)(d0 + i) * 1024 + c0 + j] = (f16)t[j * 65 + i];
  }
}

__global__ void finalize_k(const u64* __restrict__ cs, const u64* __restrict__ gs,
                           float* __restrict__ out) {
  const int lane = threadIdx.x;  // 64
  u64 c = cs[lane] + cs[lane + 64] + cs[lane + 128] + cs[lane + 192];
  u64 g = gs[lane];
#pragma unroll
  for (int o = 1; o < 64; o <<= 1) {
    c += __shfl_xor(c, o);
    g += __shfl_xor(g, o);
  }
  if (lane == 0) {
    const double commit = (double)c / 65536.0 / 67108864.0;
    const double ortho = (double)g / 16777216.0 / 4194304.0 - (1.0 / 1024.0);
    out[11927552] = (float)(commit + 0.8 * ortho);
  }
}

__global__ void ws_fail_k(float* out) {
  if (threadIdx.x == 0) out[11927552] = -777777.0f;  // sentinel: ws too small
}

// ---------------------------------------------------------------------------
extern "C" void kernel_launch(void* const* d_in, const int* in_sizes, int n_in,
                              void* d_out, int out_size, void* d_ws, size_t ws_size,
                              hipStream_t stream) {
  (void)in_sizes; (void)n_in; (void)out_size;
  const float* x = (const float*)d_in[0];
  const float* w_in = (const float*)d_in[1];
  const float* b_in = (const float*)d_in[2];
  const float* embed = (const float*)d_in[3];
  const float* w_out = (const float*)d_in[4];
  const float* b_out = (const float*)d_in[5];
  const float* w_lin = (const float*)d_in[6];
  const float* b_lin = (const float*)d_in[7];
  float* out = (float*)d_out;
  char* ws = (char*)d_ws;

  constexpr size_t SZ_WIN = 2097152, SZ_EFT = 4194304, SZ_WOUT = 2097152;
  constexpr size_t SZ_EP = 4194304, SZ_WLIN = 1572864, SZ_NT = 4194304;
  constexpr size_t SZ_SMALL = 16384 + 16384 + 524288 + 2048 + 512;
  constexpr size_t FIXED = SZ_WIN * 2 + SZ_EFT + SZ_WOUT + SZ_EP + SZ_WLIN + SZ_NT + SZ_SMALL;

  int CH = 16384, shCH = 14;
  if (ws_size < FIXED + (size_t)16384 * 12288) { CH = 8192; shCH = 13; }
  if (ws_size < FIXED + (size_t)CH * 12288) {
    ws_fail_k<<<1, 64, 0, stream>>>(out);
    return;
  }

  size_t off = 0;
  f16* x0h = (f16*)(ws + off); off += (size_t)CH * 1024;
  f16* x0l = (f16*)(ws + off); off += (size_t)CH * 1024;
  f16* fh = (f16*)(ws + off); off += (size_t)CH * 4096;
  f16* fl = (f16*)(ws + off); off += (size_t)CH * 4096;
  u64* cand = (u64*)(ws + off); off += (size_t)CH * 2048;
  f16* winh = (f16*)(ws + off); off += SZ_WIN;
  f16* winl = (f16*)(ws + off); off += SZ_WIN;
  f16* eft = (f16*)(ws + off); off += SZ_EFT;
  f16* wout = (f16*)(ws + off); off += SZ_WOUT;
  f16* Ep = (f16*)(ws + off); off += SZ_EP;
  f16* wlint = (f16*)(ws + off); off += SZ_WLIN;
  f16* nT = (f16*)(ws + off); off += SZ_NT;
  float* esq = (float*)(ws + off); off += 16384;
  float* invn = (float*)(ws + off); off += 16384;
  int* indw = (int*)(ws + off); off += 524288;
  u64* cslots = (u64*)(ws + off); off += 2048;
  u64* gslots = (u64*)(ws + off); off += 512;
  f16* qT = (f16*)ws;  // 32MB alias over x0/f after last rescore

  hipMemsetAsync((void*)cslots, 0, 2560, stream);

  prep_win<<<1024, 256, 0, stream>>>(w_in, winh, winl);
  prep_embed_k<<<1024, 256, 0, stream>>>(embed, eft, esq, invn);
  prep_normT<<<512, 256, 0, stream>>>(embed, invn, nT);
  prep_wout<<<512, 256, 0, stream>>>(w_out, wout);
  prep_wlin<<<384, 256, 0, stream>>>(w_lin, wlint);

  // Ep = embed @ w_out^T per head  (plain [4096][512])
  gemm2<1><<<128, 256, 0, stream>>>(eft, nullptr, wout, nullptr, 0,
                                    Ep, nullptr, nullptr, nullptr, nullptr);
  // ortho: ||N_h^T N_h||_F^2
  gemm2<2><<<64, 256, 0, stream>>>(nT, nullptr, nT, nullptr, 0,
                                   nullptr, nullptr, nullptr, nullptr, gslots);

  for (int c0 = 0; c0 < 32768; c0 += CH) {
    prep_x0<<<CH / 4, 256, 0, stream>>>(x, c0, x0h, x0l);
    // f = ((x-seq_last)@w_in^T + b_in), split-f16 3-pass, all heads
    gemm2<0><<<(CH / 128) * 16, 256, 0, stream>>>(x0h, x0l, winh, winl, CH,
                                                  fh, fl, b_in, nullptr, nullptr);
    // candidates buffer: empty slots = 0xFF (sparse writes from screen)
    hipMemsetAsync((void*)cand, 0xFF, (size_t)CH * 2048, stream);
    // screen: scores + margin candidates (256x128 blocks, head-major)
    gemm2<3><<<(CH / 256) * 32, 256, 0, stream>>>(fh, nullptr, eft, nullptr, CH,
                                                  cand, nullptr, nullptr, esq, nullptr);
    // exact rescore -> indices + commit d^2
    rescore_k<<<CH, 256, 0, stream>>>(cand, fh, fl, embed, c0, shCH,
                                      indw, out + 11796480, cslots);
  }

  quantize_qT<<<512, 256, 0, stream>>>(indw, Ep, b_out, qT);
  // y = w_lin @ quantized + b_lin + seq_last
  gemm2<4><<<768, 256, 0, stream>>>(wlint, nullptr, qT, nullptr, 0,
                                    out, nullptr, b_lin, x, nullptr);
  finalize_k<<<1, 64, 0, stream>>>(cslots, gslots, out);
}

// Round 7
// 697.536 us; speedup vs baseline: 1.3419x; 1.0016x over previous
//
#include <hip/hip_runtime.h>
#include <stdint.h>

typedef unsigned int u32;
typedef unsigned long long u64;
typedef _Float16 f16;
typedef __attribute__((ext_vector_type(8))) _Float16 f16x8;
typedef __attribute__((ext_vector_type(4))) _Float16 f16x4;
typedef __attribute__((ext_vector_type(2))) _Float16 f16x2;
typedef __attribute__((ext_vector_type(4))) float f32x4;

#define MFMA16(a, b, c) __builtin_amdgcn_mfma_f32_16x16x32_f16((a), (b), (c), 0, 0, 0)
#define MARGIN 2.0f
#define WAITV(n) asm volatile("s_waitcnt vmcnt(" #n ")" ::: "memory")

__device__ __forceinline__ u32 ford(float x) { u32 u = __float_as_uint(x); return (u & 0x80000000u) ? ~u : (u | 0x80000000u); }
__device__ __forceinline__ float iford(u32 v) { u32 u = (v & 0x80000000u) ? (v & 0x7FFFFFFFu) : ~v; return __uint_as_float(u); }
__device__ __forceinline__ int xswz(int i, int n) { return (i & 7) * (n >> 3) + (i >> 3); }  // n%8==0

typedef __attribute__((address_space(1))) const unsigned char ga_t;
typedef __attribute__((address_space(3))) unsigned char la_t;
__device__ __forceinline__ void gl16(const void* g, void* l) {
  __builtin_amdgcn_global_load_lds((ga_t*)g, (la_t*)l, 16, 0, 0);
}

// ---- 512-thread panel stage: 128 rows x 64 cols f16 (16KB), row stride 512 f16.
// LDS slot (r, s16B) holds global 16B-slot s ^ (r&7) (inverse swizzle on source).
__device__ __forceinline__ void stgp(const f16* g, int kt, char* sdst, int tid) {
#pragma unroll
  for (int it = 0; it < 2; ++it) {
    const int u = (tid + (it << 9)) << 4;  // [0, 16384)
    const int r = u >> 7, sl = (u >> 4) & 7;
    const char* src = (const char*)g + (size_t)r * 1024 + ((size_t)kt << 7) +
                      (size_t)((sl ^ (r & 7)) << 4);
    gl16(src, sdst + u);
  }
}

// swizzled LDS frag read: panel byte base pb, row rr in [0,128), ksub in {0,1}
__device__ __forceinline__ f16x8 rdf(const char* bb, int pb, int rr, int ks, int lane) {
  return *(const f16x8*)(bb + pb + rr * 128 +
                         ((((ks << 2) + (lane >> 4)) ^ (rr & 7)) << 4));
}

// ---------------------------------------------------------------------------
// 8-phase NT-GEMM (m201 template): 512 thr = 8 waves, BK=64, dbuf 2x64KB LDS,
// panel-granular prefetch, ONE vmcnt(0)+s_barrier per K-tile, setprio on MFMA.
// ISK1=true : 128x128 tile, 3-pass split (Ahi,Alo,Bhi,Blo) -> f16 hi/lo out.
// ISK1=false: 256x256 screen tile, score=esq-2S, sparse margin candidates.
// ---------------------------------------------------------------------------
template <bool ISK1>
__global__ __launch_bounds__(512, 1) void gemm8(
    const f16* __restrict__ A0, const f16* __restrict__ A1,
    const f16* __restrict__ B0, const f16* __restrict__ B1,
    int chrows, void* __restrict__ out0, void* __restrict__ out1,
    const float* __restrict__ bias, const float* __restrict__ aux) {
  __shared__ char lds[131072 + (ISK1 ? 0 : 4096)];
  const int tid = threadIdx.x;
  const int lane = tid & 63, wid = tid >> 6;
  const int wm = wid >> 2, wn = wid & 3;

  int blkm, blkn, z = 0;
  {
    const int s = xswz(blockIdx.x, gridDim.x);
    if constexpr (ISK1) { blkn = s & 15; blkm = s >> 4; }
    else {
      const int bph = (chrows >> 8) << 2;  // blocks per head
      z = s / bph;
      const int rem = s - z * bph;
      blkm = rem >> 2; blkn = rem & 3;
    }
  }

  if constexpr (!ISK1) {  // candidate counters [256 rows][4 waves-n]
    ((int*)(lds + 131072))[tid] = 0;
    ((int*)(lds + 131072))[tid + 512] = 0;
  }

  // panel global bases (row stride 512 f16)
  const f16 *p0, *p1, *p2, *p3;
  if constexpr (ISK1) {
    p0 = A0 + (size_t)blkm * 65536;  // x0h 128-row band
    p1 = A1 + (size_t)blkm * 65536;  // x0l
    p2 = B0 + (size_t)blkn * 65536;  // winh 128-col band
    p3 = B1 + (size_t)blkn * 65536;  // winl
  } else {
    p0 = A0 + ((size_t)z * chrows + (size_t)blkm * 256) * 512;  // fh rows 0-127
    p1 = p0 + 65536;                                            // rows 128-255
    p2 = B0 + (size_t)z * 524288 + (size_t)blkn * 131072;       // eft codes 0-127
    p3 = p2 + 65536;                                            // codes 128-255
  }

  constexpr int NACC = ISK1 ? 8 : 32;
  f32x4 acc[NACC];
#pragma unroll
  for (int i = 0; i < NACC; ++i) acc[i] = f32x4{0.f, 0.f, 0.f, 0.f};

  // prologue: stage K-tile 0 into buffer 0
  stgp(p0, 0, lds + 0, tid);
  stgp(p1, 0, lds + 16384, tid);
  stgp(p2, 0, lds + 32768, tid);
  stgp(p3, 0, lds + 49152, tid);

#pragma unroll
  for (int kc = 0; kc < 8; ++kc) {
    const char* bb = lds + (kc & 1) * 65536;
    char* nb = lds + ((kc + 1) & 1) * 65536;
    const bool pf = (kc + 1 < 8);
    WAITV(0);                       // K-tile kc fully landed (issued 1 iter ago)
    __builtin_amdgcn_s_barrier();   // raw barrier: new stages issue after this

    if constexpr (!ISK1) {
      // ---- screen: per-wave 128x64 (mt 0..7, nt 0..3), 4 phases x 16 MFMA ----
      f16x8 a[4][2], b[4][2];
      const int pbA = wm * 16384;
      const int pbB = 32768 + (wn >> 1) * 16384;
      const int rB = (wn & 1) * 64 + (lane & 15);
      // P0: read A mt0-3 + B nt0-1; stage panel0; MFMA mt0-3 x nt0-1
#pragma unroll
      for (int mt = 0; mt < 4; ++mt)
#pragma unroll
        for (int ks = 0; ks < 2; ++ks) a[mt][ks] = rdf(bb, pbA, mt * 16 + (lane & 15), ks, lane);
#pragma unroll
      for (int nt = 0; nt < 2; ++nt)
#pragma unroll
        for (int ks = 0; ks < 2; ++ks) b[nt][ks] = rdf(bb, pbB, rB + nt * 16, ks, lane);
      if (pf) stgp(p0, kc + 1, nb + 0, tid);
      __builtin_amdgcn_s_setprio(1);
#pragma unroll
      for (int nt = 0; nt < 2; ++nt)
#pragma unroll
        for (int mt = 0; mt < 4; ++mt)
#pragma unroll
          for (int ks = 0; ks < 2; ++ks) acc[mt * 4 + nt] = MFMA16(a[mt][ks], b[nt][ks], acc[mt * 4 + nt]);
      __builtin_amdgcn_s_setprio(0);
      // P1: read B nt2-3; stage panel1; MFMA mt0-3 x nt2-3
#pragma unroll
      for (int nt = 2; nt < 4; ++nt)
#pragma unroll
        for (int ks = 0; ks < 2; ++ks) b[nt][ks] = rdf(bb, pbB, rB + nt * 16, ks, lane);
      if (pf) stgp(p1, kc + 1, nb + 16384, tid);
      __builtin_amdgcn_s_setprio(1);
#pragma unroll
      for (int nt = 2; nt < 4; ++nt)
#pragma unroll
        for (int mt = 0; mt < 4; ++mt)
#pragma unroll
          for (int ks = 0; ks < 2; ++ks) acc[mt * 4 + nt] = MFMA16(a[mt][ks], b[nt][ks], acc[mt * 4 + nt]);
      __builtin_amdgcn_s_setprio(0);
      // P2: read A mt4-7; stage panel2; MFMA mt4-7 x nt2-3
#pragma unroll
      for (int mt = 0; mt < 4; ++mt)
#pragma unroll
        for (int ks = 0; ks < 2; ++ks) a[mt][ks] = rdf(bb, pbA, (mt + 4) * 16 + (lane & 15), ks, lane);
      if (pf) stgp(p2, kc + 1, nb + 32768, tid);
      __builtin_amdgcn_s_setprio(1);
#pragma unroll
      for (int nt = 2; nt < 4; ++nt)
#pragma unroll
        for (int mt = 0; mt < 4; ++mt)
#pragma unroll
          for (int ks = 0; ks < 2; ++ks) acc[(mt + 4) * 4 + nt] = MFMA16(a[mt][ks], b[nt][ks], acc[(mt + 4) * 4 + nt]);
      __builtin_amdgcn_s_setprio(0);
      // P3: stage panel3; MFMA mt4-7 x nt0-1
      if (pf) stgp(p3, kc + 1, nb + 49152, tid);
      __builtin_amdgcn_s_setprio(1);
#pragma unroll
      for (int nt = 0; nt < 2; ++nt)
#pragma unroll
        for (int mt = 0; mt < 4; ++mt)
#pragma unroll
          for (int ks = 0; ks < 2; ++ks) acc[(mt + 4) * 4 + nt] = MFMA16(a[mt][ks], b[nt][ks], acc[(mt + 4) * 4 + nt]);
      __builtin_amdgcn_s_setprio(0);
    } else {
      // ---- K1: per-wave 64x32 (mt 0..3, nt 0..1), 3-pass, 4 phases x 12 MFMA ----
      f16x8 ah[2][2], al[2][2], bh[2][2], bl[2][2];
      const int rA = wm * 64 + (lane & 15);
      const int rB = wn * 32 + (lane & 15);
      // P0: read A(hi,lo) mt0-1 + B(hi,lo) nt0; stage p0; MFMA (mt0-1, nt0)
#pragma unroll
      for (int mt = 0; mt < 2; ++mt)
#pragma unroll
        for (int ks = 0; ks < 2; ++ks) {
          ah[mt][ks] = rdf(bb, 0, rA + mt * 16, ks, lane);
          al[mt][ks] = rdf(bb, 16384, rA + mt * 16, ks, lane);
        }
#pragma unroll
      for (int ks = 0; ks < 2; ++ks) {
        bh[0][ks] = rdf(bb, 32768, rB, ks, lane);
        bl[0][ks] = rdf(bb, 49152, rB, ks, lane);
      }
      if (pf) stgp(p0, kc + 1, nb + 0, tid);
      __builtin_amdgcn_s_setprio(1);
#pragma unroll
      for (int mt = 0; mt < 2; ++mt)
#pragma unroll
        for (int ks = 0; ks < 2; ++ks) {
          acc[mt * 2] = MFMA16(al[mt][ks], bh[0][ks], acc[mt * 2]);
          acc[mt * 2] = MFMA16(ah[mt][ks], bl[0][ks], acc[mt * 2]);
          acc[mt * 2] = MFMA16(ah[mt][ks], bh[0][ks], acc[mt * 2]);
        }
      __builtin_amdgcn_s_setprio(0);
      // P1: read B nt1; stage p1; MFMA (mt0-1, nt1)
#pragma unroll
      for (int ks = 0; ks < 2; ++ks) {
        bh[1][ks] = rdf(bb, 32768, rB + 16, ks, lane);
        bl[1][ks] = rdf(bb, 49152, rB + 16, ks, lane);
      }
      if (pf) stgp(p1, kc + 1, nb + 16384, tid);
      __builtin_amdgcn_s_setprio(1);
#pragma unroll
      for (int mt = 0; mt < 2; ++mt)
#pragma unroll
        for (int ks = 0; ks < 2; ++ks) {
          acc[mt * 2 + 1] = MFMA16(al[mt][ks], bh[1][ks], acc[mt * 2 + 1]);
          acc[mt * 2 + 1] = MFMA16(ah[mt][ks], bl[1][ks], acc[mt * 2 + 1]);
          acc[mt * 2 + 1] = MFMA16(ah[mt][ks], bh[1][ks], acc[mt * 2 + 1]);
        }
      __builtin_amdgcn_s_setprio(0);
      // P2: read A mt2-3; stage p2; MFMA (mt2-3, nt1)
#pragma unroll
      for (int mt = 0; mt < 2; ++mt)
#pragma unroll
        for (int ks = 0; ks < 2; ++ks) {
          ah[mt][ks] = rdf(bb, 0, rA + (mt + 2) * 16, ks, lane);
          al[mt][ks] = rdf(bb, 16384, rA + (mt + 2) * 16, ks, lane);
        }
      if (pf) stgp(p2, kc + 1, nb + 32768, tid);
      __builtin_amdgcn_s_setprio(1);
#pragma unroll
      for (int mt = 0; mt < 2; ++mt)
#pragma unroll
        for (int ks = 0; ks < 2; ++ks) {
          acc[(mt + 2) * 2 + 1] = MFMA16(al[mt][ks], bh[1][ks], acc[(mt + 2) * 2 + 1]);
          acc[(mt + 2) * 2 + 1] = MFMA16(ah[mt][ks], bl[1][ks], acc[(mt + 2) * 2 + 1]);
          acc[(mt + 2) * 2 + 1] = MFMA16(ah[mt][ks], bh[1][ks], acc[(mt + 2) * 2 + 1]);
        }
      __builtin_amdgcn_s_setprio(0);
      // P3: stage p3; MFMA (mt2-3, nt0)
      if (pf) stgp(p3, kc + 1, nb + 49152, tid);
      __builtin_amdgcn_s_setprio(1);
#pragma unroll
      for (int mt = 0; mt < 2; ++mt)
#pragma unroll
        for (int ks = 0; ks < 2; ++ks) {
          acc[(mt + 2) * 2] = MFMA16(al[mt][ks], bh[0][ks], acc[(mt + 2) * 2]);
          acc[(mt + 2) * 2] = MFMA16(ah[mt][ks], bl[0][ks], acc[(mt + 2) * 2]);
          acc[(mt + 2) * 2] = MFMA16(ah[mt][ks], bh[0][ks], acc[(mt + 2) * 2]);
        }
      __builtin_amdgcn_s_setprio(0);
    }
  }

  // ---- epilogues ---- C/D: col = lane&15, row = (lane>>4)*4 + reg
  if constexpr (ISK1) {
    f16* fh = (f16*)out0;
    f16* fl = (f16*)out1;
#pragma unroll
    for (int nt = 0; nt < 2; ++nt) {
      const int gc = blkn * 128 + wn * 32 + nt * 16 + (lane & 15);
      const float bv = bias[gc];
      const int h = gc >> 9, d = gc & 511;
#pragma unroll
      for (int mt = 0; mt < 4; ++mt)
#pragma unroll
        for (int r = 0; r < 4; ++r) {
          const int grow = blkm * 128 + wm * 64 + mt * 16 + ((lane >> 4) << 2) + r;
          const float v = acc[mt * 2 + nt][r] * 6.103515625e-05f + bv;  // /16384 exact
          const f16 hv = (f16)v;
          const size_t off = ((size_t)h * chrows + grow) * 512 + d;
          fh[off] = hv;
          fl[off] = (f16)(v - (float)hv);
        }
    }
  } else {
    int* cntL = (int*)(lds + 131072);
    u64* candG = (u64*)out0;
    const int h = z;
    float escol[4];
    int cc[4];
#pragma unroll
    for (int nt = 0; nt < 4; ++nt) {
      cc[nt] = blkn * 256 + wn * 64 + nt * 16 + (lane & 15);  // code idx in head
      escol[nt] = aux[h * 1024 + cc[nt]];
    }
#pragma unroll
    for (int mt = 0; mt < 8; ++mt)
#pragma unroll
      for (int r = 0; r < 4; ++r) {
        const int row_l = wm * 128 + mt * 16 + ((lane >> 4) << 2) + r;  // [0,256)
        float vals[4];
        float mn = 3.4e38f;
#pragma unroll
        for (int nt = 0; nt < 4; ++nt) {
          const float v = escol[nt] - 2.0f * acc[mt * 4 + nt][r];
          vals[nt] = v;
          mn = fminf(mn, v);
        }
#pragma unroll
        for (int o = 1; o < 16; o <<= 1) mn = fminf(mn, __shfl_xor(mn, o));
        const float lim = mn + MARGIN;
#pragma unroll
        for (int nt = 0; nt < 4; ++nt)
          if (vals[nt] <= lim) {
            const int p = atomicAdd(&cntL[row_l * 4 + wn], 1);
            if (p < 4) {
              const size_t grow = (size_t)blkm * 256 + row_l;
              candG[((size_t)h * chrows + grow) * 64 + blkn * 16 + wn * 4 + p] =
                  ((u64)ford(vals[nt]) << 32) | (u32)cc[nt];
            }
          }
      }
  }
}

// ---------------------------------------------------------------------------
// small GEMM (modes 1,2,4) — unchanged 2-phase core, BK=32, 256 thr
// ---------------------------------------------------------------------------
template <int LDK>
__device__ __forceinline__ void stg8k(const f16* gRowBase, int ktile, char* sdst, int tid) {
#pragma unroll
  for (int it = 0; it < 2; ++it) {
    const int u = (tid + (it << 8)) << 4;
    const int r = u >> 6, s = (u >> 4) & 3;
    const char* src = (const char*)gRowBase + (size_t)r * (LDK * 2) + ((size_t)ktile << 6) +
                      (size_t)((s ^ ((r >> 1) & 3)) << 4);
    gl16(src, sdst + u);
  }
}

template <int MODE>
__global__ __launch_bounds__(256, 3) void gemm2(
    const f16* __restrict__ Ah, const f16* __restrict__ Bh,
    void* __restrict__ out0, const float* __restrict__ bias,
    const float* __restrict__ aux, u64* __restrict__ slots) {
  constexpr int LDK = (MODE == 2 || MODE == 4) ? 1024 : 512;
  constexpr int D = 3;
  constexpr int KT = (MODE == 2 || MODE == 4) ? 32 : 16;
  constexpr int BUF = 16384;
  __shared__ char lds[D * BUF];

  const int tid = threadIdx.x;
  const int lane = tid & 63, wid = tid >> 6;
  const int wm = wid >> 1, wn = wid & 1;

  int blkm, blkn, z = 0;
  {
    const int s = xswz(blockIdx.x, gridDim.x);
    if constexpr (MODE == 1) { blkn = s & 3; blkm = s >> 2; z = blkm >> 3; }
    else if constexpr (MODE == 2) { blkn = s & 3; blkm = (s >> 2) & 3; z = s >> 4; }
    else { const int r2 = s % 24; blkm = r2 % 6; blkn = r2 / 6; z = s / 24; }
  }

  const f16 *Ab, *Bb;
  if constexpr (MODE == 1) {
    Ab = Ah + (size_t)blkm * 65536;
    Bb = Bh + (size_t)z * 262144 + (size_t)blkn * 65536;
  } else if constexpr (MODE == 2) {
    Ab = Ah + (size_t)z * 524288 + (size_t)blkm * 131072;
    Bb = Bh + (size_t)z * 524288 + (size_t)blkn * 131072;
  } else {
    Ab = Ah + (size_t)blkm * 131072;
    Bb = Bh + (size_t)z * 524288 + (size_t)blkn * 131072;
  }

  f32x4 acc[4][4];
#pragma unroll
  for (int i = 0; i < 4; ++i)
#pragma unroll
    for (int j = 0; j < 4; ++j) acc[i][j] = f32x4{0.f, 0.f, 0.f, 0.f};

  auto stage = [&](int kt, char* nb) {
    stg8k<LDK>(Ab, kt, nb, tid);
    stg8k<LDK>(Bb, kt, nb + 8192, tid);
  };
#pragma unroll
  for (int d = 0; d < D - 1; ++d) stage(d, lds + d * BUF);

#pragma unroll
  for (int kc = 0; kc < KT; ++kc) {
    if (kc + D - 1 < KT) stage(kc + D - 1, lds + ((kc + D - 1) % D) * BUF);
    const int nf = KT - 1 - kc;
    if (nf >= 2) WAITV(8);
    else if (nf == 1) WAITV(4);
    else WAITV(0);
    __builtin_amdgcn_s_barrier();
    const char* cbuf = lds + (kc % D) * BUF;
    f16x8 ah[4];
#pragma unroll
    for (int mt = 0; mt < 4; ++mt) {
      const int rr = wm * 64 + mt * 16 + (lane & 15);
      ah[mt] = *(const f16x8*)(cbuf + rr * 64 + (((lane >> 4) ^ ((rr >> 1) & 3)) << 4));
    }
    __builtin_amdgcn_s_setprio(1);
#pragma unroll
    for (int nt = 0; nt < 4; ++nt) {
      const int rn = wn * 64 + nt * 16 + (lane & 15);
      const f16x8 bh = *(const f16x8*)(cbuf + 8192 + rn * 64 + (((lane >> 4) ^ ((rn >> 1) & 3)) << 4));
#pragma unroll
      for (int mt = 0; mt < 4; ++mt) acc[mt][nt] = MFMA16(ah[mt], bh, acc[mt][nt]);
    }
    __builtin_amdgcn_s_setprio(0);
    __builtin_amdgcn_s_barrier();
  }

  if constexpr (MODE == 1) {
    f16* o = (f16*)out0;
#pragma unroll
    for (int nt = 0; nt < 4; ++nt) {
      const int gc = blkn * 128 + wn * 64 + nt * 16 + (lane & 15);
#pragma unroll
      for (int mt = 0; mt < 4; ++mt)
#pragma unroll
        for (int r = 0; r < 4; ++r) {
          const size_t grow = (size_t)blkm * 128 + wm * 64 + mt * 16 + ((lane >> 4) << 2) + r;
          o[grow * 512 + gc] = (f16)acc[mt][nt][r];
        }
    }
  } else if constexpr (MODE == 2) {
    float ssum = 0.f;
#pragma unroll
    for (int mt = 0; mt < 4; ++mt)
#pragma unroll
      for (int nt = 0; nt < 4; ++nt)
#pragma unroll
        for (int r = 0; r < 4; ++r) ssum += acc[mt][nt][r] * acc[mt][nt][r];
#pragma unroll
    for (int o = 1; o < 64; o <<= 1) ssum += __shfl_xor(ssum, o);
    float* wp = (float*)lds;
    __syncthreads();
    if (lane == 0) wp[wid] = ssum;
    __syncthreads();
    if (tid == 0) {
      const float p = wp[0] + wp[1] + wp[2] + wp[3];
      atomicAdd(slots + (blockIdx.x & 63), (u64)llrintf(p * 16777216.f));
    }
  } else {
    float* oy = (float*)out0 + (size_t)z * 368640;
    const float* xseq = aux + (size_t)z * 524288 + 523776;
    float sl[4];
    int gd[4];
#pragma unroll
    for (int nt = 0; nt < 4; ++nt) {
      gd[nt] = blkn * 128 + wn * 64 + nt * 16 + (lane & 15);
      sl[nt] = xseq[gd[nt]];
    }
#pragma unroll
    for (int mt = 0; mt < 4; ++mt)
#pragma unroll
      for (int r = 0; r < 4; ++r) {
        const int p = blkm * 128 + wm * 64 + mt * 16 + ((lane >> 4) << 2) + r;
        if (p < 720) {
          const float bp = bias[p];
#pragma unroll
          for (int nt = 0; nt < 4; ++nt) oy[(size_t)p * 512 + gd[nt]] = acc[mt][nt][r] + bp + sl[nt];
        }
      }
  }
}

// ---------------------------------------------------------------------------
// Rescore: exact fp64 distances (f = fh+fl vs fp32 embed) over margin set.
// ---------------------------------------------------------------------------
__global__ __launch_bounds__(256, 4) void rescore_k(
    const u64* __restrict__ candG, const f16* __restrict__ fh,
    const f16* __restrict__ fl, const float* __restrict__ embed,
    int n0, int shCH,
    int* __restrict__ indw, float* __restrict__ indout, u64* __restrict__ cslots) {
  const int tid = threadIdx.x, lane = tid & 63, wid = tid >> 6;
  const int r = blockIdx.x * 4 + wid;  // r = h*CH + row
  const int h = r >> shCH, row = r & ((1 << shCH) - 1);
  u64 cu = candG[(size_t)r * 64 + lane];
  u64 mn = cu;
#pragma unroll
  for (int o = 1; o < 64; o <<= 1) { const u64 t = __shfl_xor(mn, o); if (t < mn) mn = t; }
  const float lim = iford((u32)(mn >> 32)) + MARGIN;
  const bool pass = iford((u32)(cu >> 32)) <= lim;  // empty slots -> NaN -> false
  u64 mask = __ballot(pass);
  float fv[8];
  {
    const size_t fo = (size_t)r * 512 + lane * 8;
    const f16x8 hv = *(const f16x8*)(fh + fo);
    const f16x8 lv = *(const f16x8*)(fl + fo);
#pragma unroll
    for (int j = 0; j < 8; ++j) fv[j] = (float)hv[j] + (float)lv[j];
  }
  double bestd = 1e300;
  int bestc = 0x7FFFFFFF;
  while (mask) {
    const int src = __ffsll((unsigned long long)mask) - 1;
    mask &= mask - 1;
    const int c = (int)(u32)__shfl(cu, src);
    const float* e = embed + ((size_t)h * 1024 + c) * 512 + lane * 8;
    const float4 e0 = *(const float4*)e, e1 = *(const float4*)(e + 4);
    const float ev[8] = {e0.x, e0.y, e0.z, e0.w, e1.x, e1.y, e1.z, e1.w};
    double sd = 0.0;
#pragma unroll
    for (int j = 0; j < 8; ++j) { const double d = (double)fv[j] - (double)ev[j]; sd += d * d; }
#pragma unroll
    for (int o = 1; o < 64; o <<= 1) sd += __shfl_xor(sd, o);
    if (sd < bestd || (sd == bestd && c < bestc)) { bestd = sd; bestc = c; }
  }
  if (lane == 0) {
    const int n = n0 + row;
    indw[(size_t)n * 4 + h] = bestc;
    indout[(size_t)n * 4 + h] = (float)bestc;
    atomicAdd(cslots + (blockIdx.x & 255), (u64)llrint(bestd * 65536.0));
  }
}

// quantized^T gather: qT[b][d][s] = f16( b_out[d] + sum_h Ep[h*1024+ind][d] )
__global__ __launch_bounds__(256) void quantize_qT(
    const int* __restrict__ indw, const f16* __restrict__ Ep,
    const float* __restrict__ b_out, f16* __restrict__ qT) {
  const int tid = threadIdx.x;
  const int b = blockIdx.x >> 4, s0 = (blockIdx.x & 15) << 6;
  __shared__ int inds[64][4];
  inds[tid >> 2][tid & 3] = indw[(size_t)(b * 1024 + s0 + (tid >> 2)) * 4 + (tid & 3)];
  __syncthreads();
  const int d0 = tid * 2;
  const float ba0 = b_out[d0], ba1 = b_out[d0 + 1];
  u32 r0[32], r1[32];
  f16 t0 = (f16)0.f, t1 = (f16)0.f;
#pragma unroll
  for (int ss = 0; ss < 64; ++ss) {
    float a0 = ba0, a1 = ba1;
#pragma unroll
    for (int h = 0; h < 4; ++h) {
      const int c = inds[ss][h];
      const f16x2 p = *(const f16x2*)(Ep + (((size_t)h * 1024 + c) * 512 + d0));
      a0 += (float)p[0];
      a1 += (float)p[1];
    }
    const f16 q0 = (f16)a0, q1 = (f16)a1;
    if (ss & 1) {
      f16x2 w0; w0[0] = t0; w0[1] = q0; __builtin_memcpy(&r0[ss >> 1], &w0, 4);
      f16x2 w1; w1[0] = t1; w1[1] = q1; __builtin_memcpy(&r1[ss >> 1], &w1, 4);
    } else { t0 = q0; t1 = q1; }
  }
  const size_t o0 = ((size_t)b * 512 + d0) * 1024 + s0;
#pragma unroll
  for (int i = 0; i < 8; ++i) {
    uint4 v; v.x = r0[4 * i]; v.y = r0[4 * i + 1]; v.z = r0[4 * i + 2]; v.w = r0[4 * i + 3];
    *(uint4*)(qT + o0 + (size_t)i * 8) = v;
  }
  const size_t o1 = o0 + 1024;
#pragma unroll
  for (int i = 0; i < 8; ++i) {
    uint4 v; v.x = r1[4 * i]; v.y = r1[4 * i + 1]; v.z = r1[4 * i + 2]; v.w = r1[4 * i + 3];
    *(uint4*)(qT + o1 + (size_t)i * 8) = v;
  }
}

// ---- prep kernels (plain row-major outputs) ----
__global__ __launch_bounds__(256) void prep_x0(const float* __restrict__ x, int n0,
                                               f16* __restrict__ ht, f16* __restrict__ lt) {
  const int id = blockIdx.x * 256 + threadIdx.x;
  const int k8 = id & 63, r = id >> 6;
  const int n = n0 + r, b = n >> 10;
  const float* ap = x + (size_t)n * 512 + k8 * 8;
  const float* sp = x + (size_t)b * 524288 + 523776 + k8 * 8;
  const float4 a0 = *(const float4*)ap, a1 = *(const float4*)(ap + 4);
  const float4 s0 = *(const float4*)sp, s1 = *(const float4*)(sp + 4);
  const float v[8] = {(a0.x - s0.x) * 16.f, (a0.y - s0.y) * 16.f, (a0.z - s0.z) * 16.f,
                      (a0.w - s0.w) * 16.f, (a1.x - s1.x) * 16.f, (a1.y - s1.y) * 16.f,
                      (a1.z - s1.z) * 16.f, (a1.w - s1.w) * 16.f};
  f16x8 hv, lv;
#pragma unroll
  for (int j = 0; j < 8; ++j) { const f16 h = (f16)v[j]; hv[j] = h; lv[j] = (f16)(v[j] - (float)h); }
  const size_t off = (size_t)r * 512 + k8 * 8;
  *(f16x8*)(ht + off) = hv;
  *(f16x8*)(lt + off) = lv;
}

__global__ __launch_bounds__(256) void prep_win(const float* __restrict__ src,
                                                f16* __restrict__ hi, f16* __restrict__ lo) {
  const size_t e = ((size_t)blockIdx.x * 256 + threadIdx.x) * 4;
  const float4 v = *(const float4*)(src + e);
  const float w[4] = {v.x * 1024.f, v.y * 1024.f, v.z * 1024.f, v.w * 1024.f};
  f16x4 hv, lv;
#pragma unroll
  for (int j = 0; j < 4; ++j) { const f16 h = (f16)w[j]; hv[j] = h; lv[j] = (f16)(w[j] - (float)h); }
  *(f16x4*)(hi + e) = hv;
  *(f16x4*)(lo + e) = lv;
}

__global__ __launch_bounds__(256) void prep_embed_k(const float* __restrict__ em,
                                                    f16* __restrict__ ef,
                                                    float* __restrict__ esq,
                                                    float* __restrict__ invn) {
  const int tid = threadIdx.x, lane = tid & 63, wid = tid >> 6;
  const int row = blockIdx.x * 4 + wid;
  const float* er = em + (size_t)row * 512 + lane * 8;
  const float4 a = *(const float4*)er, b = *(const float4*)(er + 4);
  f16x8 v;
  v[0] = (f16)a.x; v[1] = (f16)a.y; v[2] = (f16)a.z; v[3] = (f16)a.w;
  v[4] = (f16)b.x; v[5] = (f16)b.y; v[6] = (f16)b.z; v[7] = (f16)b.w;
  *(f16x8*)(ef + (size_t)row * 512 + lane * 8) = v;
  float s = a.x * a.x + a.y * a.y + a.z * a.z + a.w * a.w +
            b.x * b.x + b.y * b.y + b.z * b.z + b.w * b.w;
#pragma unroll
  for (int o = 1; o < 64; o <<= 1) s += __shfl_xor(s, o);
  if (lane == 0) { esq[row] = s; invn[row] = 1.0f / sqrtf(s); }
}

__global__ __launch_bounds__(256) void prep_wout(const float* __restrict__ src,
                                                 f16* __restrict__ dst) {
  const int id = blockIdx.x * 256 + threadIdx.x;
  const int k8 = id & 63, rg = id >> 6;
  const int d = rg & 511, h = rg >> 9;
  const float* ap = src + (size_t)d * 2048 + h * 512 + k8 * 8;
  const float4 a0 = *(const float4*)ap, a1 = *(const float4*)(ap + 4);
  f16x8 v;
  v[0] = (f16)a0.x; v[1] = (f16)a0.y; v[2] = (f16)a0.z; v[3] = (f16)a0.w;
  v[4] = (f16)a1.x; v[5] = (f16)a1.y; v[6] = (f16)a1.z; v[7] = (f16)a1.w;
  *(f16x8*)(dst + (size_t)h * 262144 + (size_t)d * 512 + k8 * 8) = v;
}

__global__ __launch_bounds__(256) void prep_wlin(const float* __restrict__ src,
                                                 f16* __restrict__ dst) {
  const int id = blockIdx.x * 256 + threadIdx.x;
  const int k8 = id & 127, row = id >> 7;
  float4 a0 = {0.f, 0.f, 0.f, 0.f}, a1 = a0;
  if (row < 720) {
    const float* ap = src + (size_t)row * 1024 + k8 * 8;
    a0 = *(const float4*)ap;
    a1 = *(const float4*)(ap + 4);
  }
  f16x8 v;
  v[0] = (f16)a0.x; v[1] = (f16)a0.y; v[2] = (f16)a0.z; v[3] = (f16)a0.w;
  v[4] = (f16)a1.x; v[5] = (f16)a1.y; v[6] = (f16)a1.z; v[7] = (f16)a1.w;
  *(f16x8*)(dst + (size_t)row * 1024 + k8 * 8) = v;
}

__global__ __launch_bounds__(256) void prep_normT(const float* __restrict__ em,
                                                  const float* __restrict__ invn,
                                                  f16* __restrict__ nT) {
  __shared__ float t[64 * 65];
  const int tid = threadIdx.x;
  const int bx = blockIdx.x;
  const int h = bx >> 7, rem = bx & 127, cb = rem >> 3, db = rem & 7;
  const int c0 = cb * 64, d0 = db * 64;
  const int j = tid & 63, i0 = tid >> 6;
#pragma unroll
  for (int p = 0; p < 16; ++p) {
    const int i = p * 4 + i0;
    t[i * 65 + j] = em[(size_t)h * 524288 + (size_t)(c0 + i) * 512 + d0 + j] * invn[h * 1024 + c0 + i];
  }
  __syncthreads();
#pragma unroll
  for (int p = 0; p < 16; ++p) {
    const int i = p * 4 + i0;
    nT[(size_t)h * 524288 + (size_t)(d0 + i) * 1024 + c0 + j] = (f16)t[j * 65 + i];
  }
}

__global__ void finalize_k(const u64* __restrict__ cs, const u64* __restrict__ gs,
                           float* __restrict__ out) {
  const int lane = threadIdx.x;
  u64 c = cs[lane] + cs[lane + 64] + cs[lane + 128] + cs[lane + 192];
  u64 g = gs[lane];
#pragma unroll
  for (int o = 1; o < 64; o <<= 1) {
    c += __shfl_xor(c, o);
    g += __shfl_xor(g, o);
  }
  if (lane == 0) {
    const double commit = (double)c / 65536.0 / 67108864.0;
    const double ortho = (double)g / 16777216.0 / 4194304.0 - (1.0 / 1024.0);
    out[11927552] = (float)(commit + 0.8 * ortho);
  }
}

__global__ void ws_fail_k(float* out) {
  if (threadIdx.x == 0) out[11927552] = -777777.0f;
}

// ---------------------------------------------------------------------------
extern "C" void kernel_launch(void* const* d_in, const int* in_sizes, int n_in,
                              void* d_out, int out_size, void* d_ws, size_t ws_size,
                              hipStream_t stream) {
  (void)in_sizes; (void)n_in; (void)out_size;
  const float* x = (const float*)d_in[0];
  const float* w_in = (const float*)d_in[1];
  const float* b_in = (const float*)d_in[2];
  const float* embed = (const float*)d_in[3];
  const float* w_out = (const float*)d_in[4];
  const float* b_out = (const float*)d_in[5];
  const float* w_lin = (const float*)d_in[6];
  const float* b_lin = (const float*)d_in[7];
  float* out = (float*)d_out;
  char* ws = (char*)d_ws;

  constexpr size_t SZ_WIN = 2097152, SZ_EFT = 4194304, SZ_WOUT = 2097152;
  constexpr size_t SZ_EP = 4194304, SZ_WLIN = 1572864, SZ_NT = 4194304;
  constexpr size_t SZ_SMALL = 16384 + 16384 + 524288 + 2048 + 512;
  constexpr size_t FIXED = SZ_WIN * 2 + SZ_EFT + SZ_WOUT + SZ_EP + SZ_WLIN + SZ_NT + SZ_SMALL;

  int CH = 16384, shCH = 14;
  if (ws_size < FIXED + (size_t)16384 * 12288) { CH = 8192; shCH = 13; }
  if (ws_size < FIXED + (size_t)CH * 12288) {
    ws_fail_k<<<1, 64, 0, stream>>>(out);
    return;
  }

  size_t off = 0;
  f16* x0h = (f16*)(ws + off); off += (size_t)CH * 1024;
  f16* x0l = (f16*)(ws + off); off += (size_t)CH * 1024;
  f16* fh = (f16*)(ws + off); off += (size_t)CH * 4096;
  f16* fl = (f16*)(ws + off); off += (size_t)CH * 4096;
  u64* cand = (u64*)(ws + off); off += (size_t)CH * 2048;
  f16* winh = (f16*)(ws + off); off += SZ_WIN;
  f16* winl = (f16*)(ws + off); off += SZ_WIN;
  f16* eft = (f16*)(ws + off); off += SZ_EFT;
  f16* wout = (f16*)(ws + off); off += SZ_WOUT;
  f16* Ep = (f16*)(ws + off); off += SZ_EP;
  f16* wlint = (f16*)(ws + off); off += SZ_WLIN;
  f16* nT = (f16*)(ws + off); off += SZ_NT;
  float* esq = (float*)(ws + off); off += 16384;
  float* invn = (float*)(ws + off); off += 16384;
  int* indw = (int*)(ws + off); off += 524288;
  u64* cslots = (u64*)(ws + off); off += 2048;
  u64* gslots = (u64*)(ws + off); off += 512;
  f16* qT = (f16*)ws;  // alias over x0/f after last rescore

  hipMemsetAsync((void*)cslots, 0, 2560, stream);

  prep_win<<<1024, 256, 0, stream>>>(w_in, winh, winl);
  prep_embed_k<<<1024, 256, 0, stream>>>(embed, eft, esq, invn);
  prep_normT<<<512, 256, 0, stream>>>(embed, invn, nT);
  prep_wout<<<512, 256, 0, stream>>>(w_out, wout);
  prep_wlin<<<384, 256, 0, stream>>>(w_lin, wlint);

  // Ep = embed @ w_out^T per head
  gemm2<1><<<128, 256, 0, stream>>>(eft, wout, Ep, nullptr, nullptr, nullptr);
  // ortho: ||N_h^T N_h||_F^2
  gemm2<2><<<64, 256, 0, stream>>>(nT, nT, nullptr, nullptr, nullptr, gslots);

  for (int c0 = 0; c0 < 32768; c0 += CH) {
    prep_x0<<<CH / 4, 256, 0, stream>>>(x, c0, x0h, x0l);
    // K1: f = ((x-seq_last)@w_in^T + b_in), split-f16 3-pass, 8-phase
    gemm8<true><<<(CH / 128) * 16, 512, 0, stream>>>(x0h, x0l, winh, winl, CH,
                                                     fh, fl, b_in, nullptr);
    hipMemsetAsync((void*)cand, 0xFF, (size_t)CH * 2048, stream);
    // screen: 256x256 8-phase, sparse margin candidates
    gemm8<false><<<(CH / 256) * 16, 512, 0, stream>>>(fh, nullptr, eft, nullptr, CH,
                                                      cand, nullptr, nullptr, esq);
    // exact rescore -> indices + commit d^2
    rescore_k<<<CH, 256, 0, stream>>>(cand, fh, fl, embed, c0, shCH,
                                      indw, out + 11796480, cslots);
  }

  quantize_qT<<<512, 256, 0, stream>>>(indw, Ep, b_out, qT);
  // y = w_lin @ quantized + b_lin + seq_last
  gemm2<4><<<768, 256, 0, stream>>>(wlint, qT, out, b_lin, x, nullptr);
  finalize_k<<<1, 64, 0, stream>>>(cslots, gslots, out);
}